// Round 11
// baseline (2706.119 us; speedup 1.0000x reference)
//
#include <hip/hip_runtime.h>
#include <hip/hip_cooperative_groups.h>

namespace cg = cooperative_groups;

__device__ __forceinline__ float silu_f(float x) { return x / (1.f + __expf(-x)); }

// ============================================================================
// Shared device pieces
// ============================================================================

// ---------------- A-operand descriptor (fallback path) ----------------
struct AOp {
  const float* P;
  const float* w1;
  const float* b0;
  int lda;
  int tgen;
};

// ---------------- 64x64 tile GEMM device core (mega path, single-buffer LDS) ----
// TG: A[m][k] = silu(tvec[m]*tw1[k] + tb0[k]).  BT: B stored [N][K].
// Caller pre-offsets Ap/tw1/tb0/Bp by the K-slab base.
template <int TG, int BT>
__device__ __forceinline__ void tile_gemm(
    float (*As)[68], float (*Bs)[68],
    const float* __restrict__ Ap, int lda,
    const float* __restrict__ tvec, const float* __restrict__ tw1,
    const float* __restrict__ tb0,
    const float* __restrict__ Bp, int ldb,
    float* __restrict__ Op, int ldc, int Kslab, int bm, int bn, float alpha) {
  const int tid = threadIdx.x;
  const int ar = tid >> 3, ak = (tid & 7) << 2;
  const int br = tid >> 4, bn4 = (tid & 15) << 2;
  const int ty = tid >> 4, tx = tid & 15;
  float acc[4][4] = {};
  float4 rA[2], rB[2], rW, rC;
  float tm0 = 0.f, tm1 = 0.f;
  if (TG) { tm0 = tvec[bm + ar]; tm1 = tvec[bm + ar + 32]; }
  auto loadA = [&](int k0) {
    int kg = k0 + ak;
    if (TG) {
      rW = *(const float4*)&tw1[kg];
      rC = *(const float4*)&tb0[kg];
    } else {
#pragma unroll
      for (int h = 0; h < 2; ++h)
        rA[h] = *(const float4*)&Ap[(long)(bm + ar + h * 32) * lda + kg];
    }
  };
  auto loadB = [&](int k0) {
    if (BT) {
#pragma unroll
      for (int h = 0; h < 2; ++h)
        rB[h] = *(const float4*)&Bp[(long)(bn + ar + h * 32) * ldb + k0 + ak];
    } else {
#pragma unroll
      for (int h = 0; h < 2; ++h)
        rB[h] = *(const float4*)&Bp[(long)(k0 + br + h * 16) * ldb + bn + bn4];
    }
  };
  loadA(0); loadB(0);
  for (int k0 = 0; k0 < Kslab; k0 += 32) {
    __syncthreads();  // previous compute done; LDS writable
#pragma unroll
    for (int h = 0; h < 2; ++h) {
      int m = ar + h * 32;
      float4 av;
      if (TG) {
        float tm = h ? tm1 : tm0;
        av.x = silu_f(tm * rW.x + rC.x);
        av.y = silu_f(tm * rW.y + rC.y);
        av.z = silu_f(tm * rW.z + rC.z);
        av.w = silu_f(tm * rW.w + rC.w);
      } else {
        av = rA[h];
      }
      As[ak + 0][m] = av.x; As[ak + 1][m] = av.y;
      As[ak + 2][m] = av.z; As[ak + 3][m] = av.w;
    }
    if (BT) {
#pragma unroll
      for (int h = 0; h < 2; ++h) {
        int n = ar + h * 32;
        Bs[ak + 0][n] = rB[h].x; Bs[ak + 1][n] = rB[h].y;
        Bs[ak + 2][n] = rB[h].z; Bs[ak + 3][n] = rB[h].w;
      }
    } else {
#pragma unroll
      for (int h = 0; h < 2; ++h) *(float4*)&Bs[br + h * 16][bn4] = rB[h];
    }
    __syncthreads();  // tile visible
    if (k0 + 32 < Kslab) { loadA(k0 + 32); loadB(k0 + 32); }
#pragma unroll
    for (int k = 0; k < 32; ++k) {
      float4 a4 = *(const float4*)&As[k][ty << 2];
      float4 b4 = *(const float4*)&Bs[k][tx << 2];
      float am[4] = {a4.x, a4.y, a4.z, a4.w};
      float bv[4] = {b4.x, b4.y, b4.z, b4.w};
#pragma unroll
      for (int i = 0; i < 4; ++i)
#pragma unroll
        for (int j = 0; j < 4; ++j) acc[i][j] = fmaf(am[i], bv[j], acc[i][j]);
    }
  }
  float* O = Op + (long)(bm + ty * 4) * ldc + bn + tx * 4;
#pragma unroll
  for (int i = 0; i < 4; ++i) {
    float4 v = {alpha * acc[i][0], alpha * acc[i][1], alpha * acc[i][2],
                alpha * acc[i][3]};
    *(float4*)&O[(long)i * ldc] = v;
  }
}

// ---------------- grid-stride slab-sum + bias + act ----------------
__device__ __forceinline__ void sum_dev(
    const float* __restrict__ P, long slabMN, int ns,
    const float* __restrict__ b0, const float* __restrict__ b1, int bsplit,
    int cmask, int act, float* __restrict__ out, int totalF4, int blkBase) {
  if ((int)blockIdx.x < blkBase) return;
  int stride = ((int)gridDim.x - blkBase) * 256;
  for (int idx = ((int)blockIdx.x - blkBase) * 256 + (int)threadIdx.x;
       idx < totalF4; idx += stride) {
    long i4 = (long)idx << 2;
    float4 s = *(const float4*)&P[i4];
    for (int si = 1; si < ns; ++si) {
      float4 pp = *(const float4*)&P[(long)si * slabMN + i4];
      s.x += pp.x; s.y += pp.y; s.z += pp.z; s.w += pp.w;
    }
    int c = (int)i4 & cmask;
    const float* bp = (b1 && c >= bsplit) ? (b1 + c - bsplit) : (b0 + c);
    float4 bb = *(const float4*)bp;
    s.x += bb.x; s.y += bb.y; s.z += bb.z; s.w += bb.w;
    if (act) {
      s.x = silu_f(s.x); s.y = silu_f(s.y);
      s.z = silu_f(s.z); s.w = silu_f(s.w);
    }
    *(float4*)&out[i4] = s;
  }
}

// ---------------- attention unit (round-9 logic, device form) ----------------
__device__ __forceinline__ void attn_dev(
    const float* __restrict__ PBq, const float* __restrict__ bq,
    const float* __restrict__ bv, const float* __restrict__ kf,
    const float* __restrict__ Mm, const float* __restrict__ vf,
    float* __restrict__ pool, int b, int h,
    float* uq, float* uls, float (*wpart)[128], float* wcol,
    float (*ppart)[64]) {
  const int tid = threadIdx.x;
  if (tid < 64) {
    int c = h * 64 + tid;
    long o = (long)b * 512 + c;
    uq[tid] = PBq[o] + PBq[262144 + o] + PBq[524288 + o] + PBq[786432 + o] + bq[c];
  }
  __syncthreads();
  if (tid < 128) {
    const float* kr = kf + (long)tid * 512 + h * 64;
    float acc = 0.f;
#pragma unroll
    for (int d4 = 0; d4 < 16; ++d4) {
      float4 kv = *(const float4*)&kr[d4 * 4];
      acc += uq[d4 * 4] * kv.x + uq[d4 * 4 + 1] * kv.y +
             uq[d4 * 4 + 2] * kv.z + uq[d4 * 4 + 3] * kv.w;
    }
    uls[tid] = 0.0125f * acc;
  }
  __syncthreads();

  const int lane = tid & 63;
  const int wave = tid >> 6;
  const float u0 = uls[lane], u1 = uls[lane + 64];

  float blo = -0.5f, bhi = 0.5f;
#pragma unroll
  for (int it = 0; it < 11; ++it) {
    float mid = 0.5f * (blo + bhi);
    int n = __popcll(__ballot(u0 >= mid)) + __popcll(__ballot(u1 >= mid));
    bool ge = (n >= 64);
    blo = ge ? mid : blo;
    bhi = ge ? bhi : mid;
  }
  const float wlo = blo - 0.014f, whi = blo + 0.014f;

  float wc0 = 0.f, wc1 = 0.f;
  const float* Mh = Mm + h * 128;
  const int i0 = wave * 32;
  float a0r = Mh[(long)i0 * 1024 + lane];
  float a1r = Mh[(long)i0 * 1024 + lane + 64];
  float b0r = Mh[(long)(i0 + 1) * 1024 + lane];
  float b1r = Mh[(long)(i0 + 1) * 1024 + lane + 64];
  for (int r = 0; r < 32; r += 2) {
    float TA0 = u0 + a0r, TA1 = u1 + a1r;
    float TB0 = u0 + b0r, TB1 = u1 + b1r;
    if (r < 30) {
      a0r = Mh[(long)(i0 + r + 2) * 1024 + lane];
      a1r = Mh[(long)(i0 + r + 2) * 1024 + lane + 64];
      b0r = Mh[(long)(i0 + r + 3) * 1024 + lane];
      b1r = Mh[(long)(i0 + r + 3) * 1024 + lane + 64];
    }
    float loA = wlo, hiA = whi, loB = wlo, hiB = whi;
#pragma unroll
    for (int it = 0; it < 5; ++it) {
      float midA = 0.5f * (loA + hiA), midB = 0.5f * (loB + hiB);
      int nA = __popcll(__ballot(TA0 >= midA)) + __popcll(__ballot(TA1 >= midA));
      int nB = __popcll(__ballot(TB0 >= midB)) + __popcll(__ballot(TB1 >= midB));
      bool gA = (nA >= 64), gB = (nB >= 64);
      loA = gA ? midA : loA; hiA = gA ? hiA : midA;
      loB = gB ? midB : loB; hiB = gB ? hiB : midB;
    }
    float pA0 = (TA0 >= loA) ? __expf(TA0 - loA) : 0.f;
    float pA1 = (TA1 >= loA) ? __expf(TA1 - loA) : 0.f;
    float pB0 = (TB0 >= loB) ? __expf(TB0 - loB) : 0.f;
    float pB1 = (TB1 >= loB) ? __expf(TB1 - loB) : 0.f;
    float sA = pA0 + pA1, sB = pB0 + pB1;
#pragma unroll
    for (int d = 1; d < 64; d <<= 1) {
      sA += __shfl_xor(sA, d);
      sB += __shfl_xor(sB, d);
    }
    float ivA = 1.f / sA, ivB = 1.f / sB;
    wc0 += pA0 * ivA + pB0 * ivB;
    wc1 += pA1 * ivA + pB1 * ivB;
  }
  wpart[wave][lane] = wc0;
  wpart[wave][lane + 64] = wc1;
  __syncthreads();
  if (tid < 128) {
    wcol[tid] = (wpart[0][tid] + wpart[1][tid] + wpart[2][tid] + wpart[3][tid]) *
                (1.f / 128.f);
  }
  __syncthreads();
  if (wave < 2) {
    int j0 = wave * 64;
    const float* vfp = vf + h * 64 + lane;
    float acc = 0.f;
#pragma unroll 8
    for (int jj = 0; jj < 64; ++jj) acc += wcol[j0 + jj] * vfp[(long)(j0 + jj) * 512];
    ppart[wave][lane] = acc;
  }
  __syncthreads();
  if (tid < 64) {
    int d = tid;
    int c = h * 64 + d;
    long o = (long)b * 512 + c;
    long vb0 = 4 * 262144;
    float v = PBq[vb0 + o] + PBq[vb0 + 262144 + o] + PBq[vb0 + 524288 + o] +
              PBq[vb0 + 786432 + o] + bv[c];
    pool[o] = 0.1f * (ppart[0][d] + ppart[1][d]) + v;
  }
  __syncthreads();
}

// ============================================================================
// Mega kernel (cooperative)
// ============================================================================
struct MegaParams {
  const float *x_t, *t_in, *te_w1, *te_b1, *te_w2, *te_b2;
  const float *fe_w1, *fe_b1, *fe_w2, *fe_b2;
  const float *fp_w1, *fp_b1, *fp_w2, *fp_b2, *fp_w3, *fp_b3;
  const float *fid, *wq, *bq, *wk, *wv, *bv, *wo, *bo;
  const float *gp_w1, *gp_b1, *gp_w2, *gp_b2, *ln_g, *ln_b;
  const float *dn_w1, *dn_b1, *dn_w2, *dn_b2, *dn_w3, *dn_b3;
  float *out, *P, *XC, *SA, *SB, *qf, *kf, *vf, *Mb;
};

__global__ __launch_bounds__(256, 4) void mega(MegaParams p) {
  cg::grid_group grid = cg::this_grid();
  __shared__ union {
    struct { float As[32][68]; float Bs[32][68]; } g;  // 34,816 B
    struct { float uq[64]; float uls[128]; float wpart[4][128];
             float wcol[128]; float ppart[2][64]; } a;
    struct { float r1[4]; float r2[4]; } l;
  } sm;
  const int w = blockIdx.x;
  const int tid = threadIdx.x;

  // 64x64-tile helpers over shared staging
  auto Gn = [&](const float* A, int lda, const float* B, int ldb, float* O,
                int ldc, int kb, int Ks, int bm, int bn) {
    tile_gemm<0, 0>(sm.g.As, sm.g.Bs, A + kb, lda, nullptr, nullptr, nullptr,
                    B + (long)kb * ldb, ldb, O, ldc, Ks, bm, bn, 1.f);
  };

  // ---- P1: qf/kf/vf (48w) || act1 s4 (256w) ----
  if (w < 48) {
    int prob = w >> 4, t = w & 15;
    const float* B = prob == 0 ? p.wq : (prob == 1 ? p.wk : p.wv);
    float* O = prob == 0 ? p.qf : (prob == 1 ? p.kf : p.vf);
    Gn(p.fid, 128, B, 512, O, 512, 0, 128, (t >> 3) * 64, (t & 7) * 64);
  } else if (w < 304) {
    int w2 = w - 48, s = w2 & 3, t = w2 >> 2;
    Gn(p.x_t, 128, p.fe_w1, 512, p.P + (long)s * 262144, 512, s * 32, 32,
       (t >> 3) * 64, (t & 7) * 64);
  }
  grid.sync();
  // ---- P2: M (32w) || SA = silu(sum4 + fe_b1) ----
  if (w < 32) {
    int h = w >> 2, t = w & 3;
    tile_gemm<0, 1>(sm.g.As, sm.g.Bs, p.qf + h * 64, 512, nullptr, nullptr,
                    nullptr, p.kf + h * 64, 512, p.Mb + h * 128, 1024, 64,
                    (t >> 1) * 64, (t & 1) * 64, 0.00125f);
  } else {
    sum_dev(p.P, 262144, 4, p.fe_b1, nullptr, 0, 511, 1, p.SA, 65536, 32);
  }
  grid.sync();
  // ---- P3: xcat (x_emb || t_emb), s4 each ----
  if (w < 512) {
    int zi = w >> 8, w2 = w & 255, s = w2 & 3, t = w2 >> 2;
    int kb = s * 128, bm = (t >> 3) * 64, bn = (t & 7) * 64;
    if (zi == 0) {
      Gn(p.SA, 512, p.fe_w2, 512, p.P + (long)s * 524288, 1024, kb, 128, bm, bn);
    } else {
      tile_gemm<1, 0>(sm.g.As, sm.g.Bs, nullptr, 0, p.t_in, p.te_w1 + kb,
                      p.te_b1 + kb, p.te_w2 + (long)kb * 512, 512,
                      p.P + (long)s * 524288 + 512, 1024, 128, bm, bn, 1.f);
    }
  }
  grid.sync();
  // ---- P4: XC = sum4 + [fe_b2|te_b2] ----
  sum_dev(p.P, 524288, 4, p.fe_b2, p.te_b2, 512, 1023, 0, p.XC, 131072, 0);
  grid.sync();
  // ---- P5: h1 s8 (K=1024) ----
  if (w < 512) {
    int s = w & 7, t = w >> 3;
    Gn(p.XC, 1024, p.fp_w1, 512, p.P + (long)s * 262144, 512, s * 128, 128,
       (t >> 3) * 64, (t & 7) * 64);
  }
  grid.sync();
  // ---- P6: SB = silu(sum8 + fp_b1) ----
  sum_dev(p.P, 262144, 8, p.fp_b1, nullptr, 0, 511, 1, p.SB, 65536, 0);
  grid.sync();
  // ---- P7: h2 s8 ----
  if (w < 512) {
    int s = w & 7, t = w >> 3;
    Gn(p.SB, 512, p.fp_w2, 512, p.P + (long)s * 262144, 512, s * 64, 64,
       (t >> 3) * 64, (t & 7) * 64);
  }
  grid.sync();
  // ---- P8: SA = silu(sum8 + fp_b2) ----
  sum_dev(p.P, 262144, 8, p.fp_b2, nullptr, 0, 511, 1, p.SA, 65536, 0);
  grid.sync();
  // ---- P9: base s8 ----
  if (w < 512) {
    int s = w & 7, t = w >> 3;
    Gn(p.SA, 512, p.fp_w3, 512, p.P + (long)s * 262144, 512, s * 64, 64,
       (t >> 3) * 64, (t & 7) * 64);
  }
  grid.sync();
  // ---- P10: SB = sum8 + fp_b3 ----
  sum_dev(p.P, 262144, 8, p.fp_b3, nullptr, 0, 511, 0, p.SB, 65536, 0);
  grid.sync();
  // ---- P11: qb & vb, s4 each -> P slabs 0-7 ----
  if (w < 512) {
    int zi = w >> 8, w2 = w & 255, s = w2 & 3, t = w2 >> 2;
    Gn(p.SB, 512, zi ? p.wv : p.wq, 512, p.P + (long)(zi * 4 + s) * 262144,
       512, s * 128, 128, (t >> 3) * 64, (t & 7) * 64);
  }
  grid.sync();
  // ---- P12: attention -> pool (SA) ----
  for (int u = w; u < 4096; u += (int)gridDim.x)
    attn_dev(p.P, p.bq, p.bv, p.kf, p.Mb, p.vf, p.SA, u >> 3, u & 7,
             sm.a.uq, sm.a.uls, sm.a.wpart, sm.a.wcol, sm.a.ppart);
  grid.sync();
  // ---- P13: g1 s8 ----
  if (w < 512) {
    int s = w & 7, t = w >> 3;
    Gn(p.SA, 512, p.wo, 512, p.P + (long)s * 262144, 512, s * 64, 64,
       (t >> 3) * 64, (t & 7) * 64);
  }
  grid.sync();
  // ---- P14: SB = sum8 + bo ----
  sum_dev(p.P, 262144, 8, p.bo, nullptr, 0, 511, 0, p.SB, 65536, 0);
  grid.sync();
  // ---- P15: g2 [512x1024] s4 ----
  if (w < 512) {
    int s = w & 3, t = w >> 2;
    Gn(p.SB, 512, p.gp_w1, 1024, p.P + (long)s * 524288, 1024, s * 128, 128,
       (t >> 4) * 64, (t & 15) * 64);
  }
  grid.sync();
  // ---- P16: XC = silu(sum4 + gp_b1) ----
  sum_dev(p.P, 524288, 4, p.gp_b1, nullptr, 0, 1023, 1, p.XC, 131072, 0);
  grid.sync();
  // ---- P17: g3 s8 (K=1024) ----
  if (w < 512) {
    int s = w & 7, t = w >> 3;
    Gn(p.XC, 1024, p.gp_w2, 512, p.P + (long)s * 262144, 512, s * 128, 128,
       (t >> 3) * 64, (t & 7) * 64);
  }
  grid.sync();
  // ---- P18: LayerNorm(sum8 + gp_b2) -> SA ----
  if (w < 512) {
    int row = w;
    long o0 = (long)row * 512 + tid, o1 = o0 + 256;
    float v0 = p.gp_b2[tid], v1 = p.gp_b2[tid + 256];
#pragma unroll
    for (int s = 0; s < 8; ++s) {
      v0 += p.P[(long)s * 262144 + o0];
      v1 += p.P[(long)s * 262144 + o1];
    }
    float s = v0 + v1;
#pragma unroll
    for (int d = 1; d < 64; d <<= 1) s += __shfl_xor(s, d);
    if ((tid & 63) == 0) sm.l.r1[tid >> 6] = s;
    __syncthreads();
    float mean = (sm.l.r1[0] + sm.l.r1[1] + sm.l.r1[2] + sm.l.r1[3]) * (1.f / 512.f);
    float d0 = v0 - mean, d1 = v1 - mean;
    float q = d0 * d0 + d1 * d1;
#pragma unroll
    for (int d = 1; d < 64; d <<= 1) q += __shfl_xor(q, d);
    if ((tid & 63) == 0) sm.l.r2[tid >> 6] = q;
    __syncthreads();
    float var = (sm.l.r2[0] + sm.l.r2[1] + sm.l.r2[2] + sm.l.r2[3]) * (1.f / 512.f);
    float inv = rsqrtf(var + 1e-5f);
    p.SA[(long)row * 512 + tid] = d0 * inv * p.ln_g[tid] + p.ln_b[tid];
    p.SA[(long)row * 512 + tid + 256] =
        d1 * inv * p.ln_g[tid + 256] + p.ln_b[tid + 256];
  }
  grid.sync();
  // ---- P19: r1 [512x1024] s4 ----
  if (w < 512) {
    int s = w & 3, t = w >> 2;
    Gn(p.SA, 512, p.dn_w1, 1024, p.P + (long)s * 524288, 1024, s * 128, 128,
       (t >> 4) * 64, (t & 15) * 64);
  }
  grid.sync();
  // ---- P20: XC = silu(sum4 + dn_b1) ----
  sum_dev(p.P, 524288, 4, p.dn_b1, nullptr, 0, 1023, 1, p.XC, 131072, 0);
  grid.sync();
  // ---- P21: r2 [1024x1024 K] s4 (Kslab 256) ----
  if (w < 512) {
    int s = w & 3, t = w >> 2;
    Gn(p.XC, 1024, p.dn_w2, 1024, p.P + (long)s * 524288, 1024, s * 256, 256,
       (t >> 4) * 64, (t & 15) * 64);
  }
  grid.sync();
  // ---- P22: XC = silu(sum4 + dn_b2) ----
  sum_dev(p.P, 524288, 4, p.dn_b2, nullptr, 0, 1023, 1, p.XC, 131072, 0);
  grid.sync();
  // ---- P23: out s16 (Kslab 64) ----
  if (w < 256) {
    int s = w & 15, t = w >> 4;
    Gn(p.XC, 1024, p.dn_w3, 256, p.P + (long)s * 65536, 128, s * 64, 64,
       (t >> 1) * 64, (t & 1) * 64);
  }
  grid.sync();
  // ---- P24: tanh(sum16 + dn_b3) -> out ----
  {
    int stride = (int)gridDim.x * 256;
    for (int idx = w * 256 + tid; idx < 16384; idx += stride) {
      long i4 = (long)idx << 2;
      float4 s = *(const float4*)&p.P[i4];
      for (int si = 1; si < 16; ++si) {
        float4 pp = *(const float4*)&p.P[(long)si * 65536 + i4];
        s.x += pp.x; s.y += pp.y; s.z += pp.z; s.w += pp.w;
      }
      int c = (int)i4 & 127;
      float4 v = {tanhf(s.x + p.dn_b3[c]), tanhf(s.y + p.dn_b3[c + 1]),
                  tanhf(s.z + p.dn_b3[c + 2]), tanhf(s.w + p.dn_b3[c + 3])};
      *(float4*)&p.out[i4] = v;
    }
  }
}

// ============================================================================
// Fallback kernels (round-10, proven at 288 us)
// ============================================================================
template <int NPROB, int T1GEN>
__global__ __launch_bounds__(256) void gemm_p(
    AOp a0, AOp a1,
    const float* __restrict__ B0, const float* __restrict__ B1,
    const float* __restrict__ B2, int ldb,
    float* __restrict__ O0, float* __restrict__ O1, float* __restrict__ O2,
    int ldc, int Kslab, int ls, long slabMN) {
  __shared__ float As[2][32][68];
  __shared__ float Bs[2][32][68];
  const int tid = threadIdx.x;
  const int z = blockIdx.z;
  const int zi = (NPROB > 1) ? (z >> ls) : 0;
  const int s = (NPROB > 1) ? (z & ((1 << ls) - 1)) : z;
  const AOp a = (NPROB > 1 && zi == 1) ? a1 : a0;
  const float* Bp = ((NPROB > 2 && zi == 2) ? B2 : (zi == 1) ? B1 : B0)
                    + (long)(s * Kslab) * ldb;
  float* Obase = ((NPROB > 2 && zi == 2) ? O2 : (zi == 1) ? O1 : O0)
                 + (long)s * slabMN;
  const int kbase = s * Kslab;
  const long bm = blockIdx.y * 64, bn = blockIdx.x * 64;
  const int tg = T1GEN ? a.tgen : 0;
  float acc[4][4] = {};
  const int ar = tid >> 3, ak = (tid & 7) << 2;
  const int br = tid >> 4, bn4 = (tid & 15) << 2;
  const int ty = tid >> 4, tx = tid & 15;
  float4 rA[2], rB[2], rW, rC;
  float tm0 = 0.f, tm1 = 0.f;
  auto loadA = [&](int k0) {
    int kg = kbase + k0 + ak;
    if (T1GEN && tg) {
      rW = *(const float4*)&a.w1[kg];
      rC = *(const float4*)&a.b0[kg];
    } else {
#pragma unroll
      for (int h = 0; h < 2; ++h)
        rA[h] = *(const float4*)&a.P[(bm + ar + h * 32) * (long)a.lda + kg];
    }
  };
  auto loadB = [&](int k0) {
#pragma unroll
    for (int h = 0; h < 2; ++h)
      rB[h] = *(const float4*)&Bp[(long)(k0 + br + h * 16) * ldb + bn + bn4];
  };
  auto store = [&](int buf) {
#pragma unroll
    for (int h = 0; h < 2; ++h) {
      int m = ar + h * 32;
      float4 av;
      if (T1GEN && tg) {
        float tm = h ? tm1 : tm0;
        av.x = silu_f(tm * rW.x + rC.x);
        av.y = silu_f(tm * rW.y + rC.y);
        av.z = silu_f(tm * rW.z + rC.z);
        av.w = silu_f(tm * rW.w + rC.w);
      } else {
        av = rA[h];
      }
      As[buf][ak + 0][m] = av.x; As[buf][ak + 1][m] = av.y;
      As[buf][ak + 2][m] = av.z; As[buf][ak + 3][m] = av.w;
    }
#pragma unroll
    for (int h = 0; h < 2; ++h) *(float4*)&Bs[buf][br + h * 16][bn4] = rB[h];
  };
  if (T1GEN && tg) { tm0 = a.P[bm + ar]; tm1 = a.P[bm + ar + 32]; }
  loadA(0); loadB(0);
  store(0);
  if (32 < Kslab) { loadA(32); loadB(32); }
  int cur = 0;
  for (int k0 = 0; k0 < Kslab; k0 += 32) {
    __syncthreads();
    if (k0 + 32 < Kslab) store(cur ^ 1);
    if (k0 + 64 < Kslab) { loadA(k0 + 64); loadB(k0 + 64); }
#pragma unroll
    for (int k = 0; k < 32; ++k) {
      float4 a4 = *(const float4*)&As[cur][k][ty << 2];
      float4 b4 = *(const float4*)&Bs[cur][k][tx << 2];
      float am[4] = {a4.x, a4.y, a4.z, a4.w};
      float bv[4] = {b4.x, b4.y, b4.z, b4.w};
#pragma unroll
      for (int i = 0; i < 4; ++i)
#pragma unroll
        for (int j = 0; j < 4; ++j) acc[i][j] = fmaf(am[i], bv[j], acc[i][j]);
    }
    cur ^= 1;
  }
  float* O = Obase + (bm + ty * 4) * (long)ldc + bn + tx * 4;
#pragma unroll
  for (int i = 0; i < 4; ++i) {
    float4 v = {acc[i][0], acc[i][1], acc[i][2], acc[i][3]};
    *(float4*)&O[(long)i * ldc] = v;
  }
}

__global__ __launch_bounds__(256) void gemm_bt(
    const float* __restrict__ A, int lda, const float* __restrict__ B, int ldb,
    float* __restrict__ OUT, int ldc, int K, float alpha,
    int zAoff, int zBoff, int zCoff) {
  __shared__ float As[2][32][68];
  __shared__ float Bs[2][32][68];
  const int tid = threadIdx.x;
  const int z = blockIdx.z;
  const long bm = blockIdx.y * 64, bn = blockIdx.x * 64;
  const float* Ab = A + (long)z * zAoff;
  const float* Bp = B + (long)z * zBoff;
  float* Obase = OUT + (long)z * zCoff;
  float acc[4][4] = {};
  const int ar = tid >> 3, ak = (tid & 7) << 2;
  const int ty = tid >> 4, tx = tid & 15;
  float4 rA[2], rB[2];
  auto loadAB = [&](int k0) {
#pragma unroll
    for (int h = 0; h < 2; ++h) {
      rA[h] = *(const float4*)&Ab[(bm + ar + h * 32) * (long)lda + k0 + ak];
      rB[h] = *(const float4*)&Bp[(bn + ar + h * 32) * (long)ldb + k0 + ak];
    }
  };
  auto store = [&](int buf) {
#pragma unroll
    for (int h = 0; h < 2; ++h) {
      int m = ar + h * 32;
      As[buf][ak + 0][m] = rA[h].x; As[buf][ak + 1][m] = rA[h].y;
      As[buf][ak + 2][m] = rA[h].z; As[buf][ak + 3][m] = rA[h].w;
      Bs[buf][ak + 0][m] = rB[h].x; Bs[buf][ak + 1][m] = rB[h].y;
      Bs[buf][ak + 2][m] = rB[h].z; Bs[buf][ak + 3][m] = rB[h].w;
    }
  };
  loadAB(0); store(0);
  if (32 < K) loadAB(32);
  int cur = 0;
  for (int k0 = 0; k0 < K; k0 += 32) {
    __syncthreads();
    if (k0 + 32 < K) store(cur ^ 1);
    if (k0 + 64 < K) loadAB(k0 + 64);
#pragma unroll
    for (int k = 0; k < 32; ++k) {
      float4 a4 = *(const float4*)&As[cur][k][ty << 2];
      float4 b4 = *(const float4*)&Bs[cur][k][tx << 2];
      float am[4] = {a4.x, a4.y, a4.z, a4.w};
      float bv[4] = {b4.x, b4.y, b4.z, b4.w};
#pragma unroll
      for (int i = 0; i < 4; ++i)
#pragma unroll
        for (int j = 0; j < 4; ++j) acc[i][j] = fmaf(am[i], bv[j], acc[i][j]);
    }
    cur ^= 1;
  }
  float* O = Obase + (bm + ty * 4) * (long)ldc + bn + tx * 4;
#pragma unroll
  for (int i = 0; i < 4; ++i) {
    float4 v = {alpha * acc[i][0], alpha * acc[i][1], alpha * acc[i][2],
                alpha * acc[i][3]};
    *(float4*)&O[(long)i * ldc] = v;
  }
}

template <int NS, int ACT>
__global__ __launch_bounds__(256) void sumk(
    const float* __restrict__ P, long slabMN,
    const float* __restrict__ b0, const float* __restrict__ b1, int bsplit,
    int cmask, float* __restrict__ out) {
  int i4 = (blockIdx.x * 256 + threadIdx.x) << 2;
  float4 s = *(const float4*)&P[i4];
#pragma unroll
  for (int si = 1; si < NS; ++si) {
    float4 pp = *(const float4*)&P[(long)si * slabMN + i4];
    s.x += pp.x; s.y += pp.y; s.z += pp.z; s.w += pp.w;
  }
  int c = i4 & cmask;
  const float* bp = (b1 && c >= bsplit) ? (b1 + c - bsplit) : (b0 + c);
  float4 bb = *(const float4*)bp;
  s.x += bb.x; s.y += bb.y; s.z += bb.z; s.w += bb.w;
  if (ACT == 1) {
    s.x = silu_f(s.x); s.y = silu_f(s.y); s.z = silu_f(s.z); s.w = silu_f(s.w);
  }
  *(float4*)&out[i4] = s;
}

__global__ __launch_bounds__(256) void reduce_tanh(
    const float* __restrict__ P, int slabMN, int nslab,
    const float* __restrict__ bias, float* __restrict__ C) {
  int i4 = (blockIdx.x * 256 + threadIdx.x) << 2;
  float4 s = *(const float4*)&P[i4];
  for (int si = 1; si < nslab; ++si) {
    float4 pp = *(const float4*)&P[(long)si * slabMN + i4];
    s.x += pp.x; s.y += pp.y; s.z += pp.z; s.w += pp.w;
  }
  int c = i4 & 127;
  float4 v = {tanhf(s.x + bias[c]), tanhf(s.y + bias[c + 1]),
              tanhf(s.z + bias[c + 2]), tanhf(s.w + bias[c + 3])};
  *(float4*)&C[i4] = v;
}

__global__ __launch_bounds__(256) void attn_kernel(
    const float* __restrict__ PBq, const float* __restrict__ bq,
    const float* __restrict__ bv, const float* __restrict__ kf,
    const float* __restrict__ Mm, const float* __restrict__ vf,
    float* __restrict__ pool) {
  __shared__ float uq[64];
  __shared__ float uls[128];
  __shared__ float wpart[4][128];
  __shared__ float wcol[128];
  __shared__ float ppart[2][64];
  attn_dev(PBq, bq, bv, kf, Mm, vf, pool, blockIdx.x, blockIdx.y,
           uq, uls, wpart, wcol, ppart);
}

template <int NSLAB>
__global__ __launch_bounds__(256) void ln_kernel(const float* __restrict__ P,
                                                 const float* __restrict__ bias,
                                                 const float* __restrict__ g,
                                                 const float* __restrict__ bb,
                                                 float* __restrict__ Y) {
  int row = blockIdx.x;
  int tid = threadIdx.x;
  long o0 = (long)row * 512 + tid;
  long o1 = o0 + 256;
  float v0 = bias[tid], v1 = bias[tid + 256];
#pragma unroll
  for (int s = 0; s < NSLAB; ++s) {
    v0 += P[(long)s * 262144 + o0];
    v1 += P[(long)s * 262144 + o1];
  }
  float s = v0 + v1;
#pragma unroll
  for (int d = 1; d < 64; d <<= 1) s += __shfl_xor(s, d);
  __shared__ float r1[4], r2[4];
  if ((tid & 63) == 0) r1[tid >> 6] = s;
  __syncthreads();
  float mean = (r1[0] + r1[1] + r1[2] + r1[3]) * (1.f / 512.f);
  float d0 = v0 - mean, d1 = v1 - mean;
  float q = d0 * d0 + d1 * d1;
#pragma unroll
  for (int d = 1; d < 64; d <<= 1) q += __shfl_xor(q, d);
  if ((tid & 63) == 0) r2[tid >> 6] = q;
  __syncthreads();
  float var = (r2[0] + r2[1] + r2[2] + r2[3]) * (1.f / 512.f);
  float inv = rsqrtf(var + 1e-5f);
  Y[(long)row * 512 + tid] = d0 * inv * g[tid] + bb[tid];
  Y[(long)row * 512 + tid + 256] = d1 * inv * g[tid + 256] + bb[tid + 256];
}

// ============================================================================
// host
// ============================================================================
extern "C" void kernel_launch(void* const* d_in, const int* in_sizes, int n_in,
                              void* d_out, int out_size, void* d_ws, size_t ws_size,
                              hipStream_t stream) {
  const float* x_t = (const float*)d_in[0];
  const float* t_in = (const float*)d_in[1];
  const float* te_w1 = (const float*)d_in[2];
  const float* te_b1 = (const float*)d_in[3];
  const float* te_w2 = (const float*)d_in[4];
  const float* te_b2 = (const float*)d_in[5];
  const float* fe_w1 = (const float*)d_in[6];
  const float* fe_b1 = (const float*)d_in[7];
  const float* fe_w2 = (const float*)d_in[8];
  const float* fe_b2 = (const float*)d_in[9];
  const float* fp_w1 = (const float*)d_in[10];
  const float* fp_b1 = (const float*)d_in[11];
  const float* fp_w2 = (const float*)d_in[12];
  const float* fp_b2 = (const float*)d_in[13];
  const float* fp_w3 = (const float*)d_in[14];
  const float* fp_b3 = (const float*)d_in[15];
  const float* fid = (const float*)d_in[16];
  const float* wq = (const float*)d_in[17];
  const float* bq = (const float*)d_in[18];
  const float* wk = (const float*)d_in[19];
  const float* wv = (const float*)d_in[21];
  const float* bv = (const float*)d_in[22];
  const float* wo = (const float*)d_in[23];
  const float* bo = (const float*)d_in[24];
  const float* gp_w1 = (const float*)d_in[25];
  const float* gp_b1 = (const float*)d_in[26];
  const float* gp_w2 = (const float*)d_in[27];
  const float* gp_b2 = (const float*)d_in[28];
  const float* ln_g = (const float*)d_in[29];
  const float* ln_b = (const float*)d_in[30];
  const float* dn_w1 = (const float*)d_in[31];
  const float* dn_b1 = (const float*)d_in[32];
  const float* dn_w2 = (const float*)d_in[33];
  const float* dn_b2 = (const float*)d_in[34];
  const float* dn_w3 = (const float*)d_in[35];
  const float* dn_b3 = (const float*)d_in[36];

  float* W = (float*)d_ws;
  float* P = W;                    // 2,097,152
  float* XC = W + 2097152;         // 524,288
  float* SA = W + 2621440;         // 262,144
  float* SB = W + 2883584;         // 262,144
  float* qf = W + 3145728;         // 65,536
  float* kf = W + 3211264;         // 65,536
  float* vf = W + 3276800;         // 65,536
  float* Mb = W + 3342336;         // 131,072

  MegaParams mp;
  mp.x_t = x_t; mp.t_in = t_in; mp.te_w1 = te_w1; mp.te_b1 = te_b1;
  mp.te_w2 = te_w2; mp.te_b2 = te_b2; mp.fe_w1 = fe_w1; mp.fe_b1 = fe_b1;
  mp.fe_w2 = fe_w2; mp.fe_b2 = fe_b2; mp.fp_w1 = fp_w1; mp.fp_b1 = fp_b1;
  mp.fp_w2 = fp_w2; mp.fp_b2 = fp_b2; mp.fp_w3 = fp_w3; mp.fp_b3 = fp_b3;
  mp.fid = fid; mp.wq = wq; mp.bq = bq; mp.wk = wk; mp.wv = wv; mp.bv = bv;
  mp.wo = wo; mp.bo = bo; mp.gp_w1 = gp_w1; mp.gp_b1 = gp_b1;
  mp.gp_w2 = gp_w2; mp.gp_b2 = gp_b2; mp.ln_g = ln_g; mp.ln_b = ln_b;
  mp.dn_w1 = dn_w1; mp.dn_b1 = dn_b1; mp.dn_w2 = dn_w2; mp.dn_b2 = dn_b2;
  mp.dn_w3 = dn_w3; mp.dn_b3 = dn_b3;
  mp.out = (float*)d_out; mp.P = P; mp.XC = XC; mp.SA = SA; mp.SB = SB;
  mp.qf = qf; mp.kf = kf; mp.vf = vf; mp.Mb = Mb;

  void* args[] = {&mp};
  hipError_t err = hipLaunchCooperativeKernel((const void*)mega, dim3(1024),
                                              dim3(256), args, 0, stream);
  if (err == hipSuccess) return;

  // ---------------- fallback: proven round-10 multi-launch path ----------------
  auto ap = [](const float* Pm, int lda) {
    AOp a; a.P = Pm; a.w1 = nullptr; a.b0 = nullptr; a.lda = lda; a.tgen = 0;
    return a;
  };
  gemm_p<3, 0><<<dim3(8, 2, 3), 256, 0, stream>>>(
      ap(fid, 128), ap(fid, 128), wq, wk, wv, 512, qf, kf, vf, 512, 128, 0, 0);
  gemm_bt<<<dim3(2, 2, 8), 256, 0, stream>>>(qf, 512, kf, 512, Mb, 1024, 64,
                                             0.00125f, 64, 64, 128);
  gemm_p<1, 0><<<dim3(8, 8, 4), 256, 0, stream>>>(
      ap(x_t, 128), ap(x_t, 128), fe_w1, nullptr, nullptr, 512,
      P, nullptr, nullptr, 512, 32, 0, 262144);
  sumk<4, 1><<<256, 256, 0, stream>>>(P, 262144, fe_b1, nullptr, 0, 511, SA);
  {
    AOp a1; a1.P = t_in; a1.w1 = te_w1; a1.b0 = te_b1; a1.lda = 0; a1.tgen = 1;
    gemm_p<2, 1><<<dim3(8, 8, 8), 256, 0, stream>>>(
        ap(SA, 512), a1, fe_w2, te_w2, nullptr, 512,
        P, P + 512, nullptr, 1024, 128, 2, 524288);
  }
  sumk<4, 0><<<512, 256, 0, stream>>>(P, 524288, fe_b2, te_b2, 512, 1023, XC);
  gemm_p<1, 0><<<dim3(8, 8, 8), 256, 0, stream>>>(
      ap(XC, 1024), ap(XC, 1024), fp_w1, nullptr, nullptr, 512,
      P, nullptr, nullptr, 512, 128, 0, 262144);
  sumk<8, 1><<<256, 256, 0, stream>>>(P, 262144, fp_b1, nullptr, 0, 511, SB);
  gemm_p<1, 0><<<dim3(8, 8, 8), 256, 0, stream>>>(
      ap(SB, 512), ap(SB, 512), fp_w2, nullptr, nullptr, 512,
      P, nullptr, nullptr, 512, 64, 0, 262144);
  sumk<8, 1><<<256, 256, 0, stream>>>(P, 262144, fp_b2, nullptr, 0, 511, SA);
  gemm_p<1, 0><<<dim3(8, 8, 8), 256, 0, stream>>>(
      ap(SA, 512), ap(SA, 512), fp_w3, nullptr, nullptr, 512,
      P, nullptr, nullptr, 512, 64, 0, 262144);
  sumk<8, 0><<<256, 256, 0, stream>>>(P, 262144, fp_b3, nullptr, 0, 511, SB);
  gemm_p<2, 0><<<dim3(8, 8, 8), 256, 0, stream>>>(
      ap(SB, 512), ap(SB, 512), wq, wv, nullptr, 512,
      P, P + 1048576, nullptr, 512, 128, 2, 262144);
  attn_kernel<<<dim3(512, 8), 256, 0, stream>>>(P, bq, bv, kf, Mb, vf, SA);
  gemm_p<1, 0><<<dim3(8, 8, 8), 256, 0, stream>>>(
      ap(SA, 512), ap(SA, 512), wo, nullptr, nullptr, 512,
      P, nullptr, nullptr, 512, 64, 0, 262144);
  sumk<8, 0><<<256, 256, 0, stream>>>(P, 262144, bo, nullptr, 0, 511, SB);
  gemm_p<1, 0><<<dim3(16, 8, 4), 256, 0, stream>>>(
      ap(SB, 512), ap(SB, 512), gp_w1, nullptr, nullptr, 1024,
      P, nullptr, nullptr, 1024, 128, 0, 524288);
  sumk<4, 1><<<512, 256, 0, stream>>>(P, 524288, gp_b1, nullptr, 0, 1023, XC);
  gemm_p<1, 0><<<dim3(8, 8, 8), 256, 0, stream>>>(
      ap(XC, 1024), ap(XC, 1024), gp_w2, nullptr, nullptr, 512,
      P, nullptr, nullptr, 512, 128, 0, 262144);
  ln_kernel<8><<<512, 256, 0, stream>>>(P, gp_b2, ln_g, ln_b, SA);
  gemm_p<1, 0><<<dim3(16, 8, 4), 256, 0, stream>>>(
      ap(SA, 512), ap(SA, 512), dn_w1, nullptr, nullptr, 1024,
      P, nullptr, nullptr, 1024, 128, 0, 524288);
  sumk<4, 1><<<512, 256, 0, stream>>>(P, 524288, dn_b1, nullptr, 0, 1023, XC);
  gemm_p<1, 0><<<dim3(16, 8, 4), 256, 0, stream>>>(
      ap(XC, 1024), ap(XC, 1024), dn_w2, nullptr, nullptr, 1024,
      P, nullptr, nullptr, 1024, 256, 0, 524288);
  sumk<4, 1><<<512, 256, 0, stream>>>(P, 524288, dn_b2, nullptr, 0, 1023, XC);
  gemm_p<1, 0><<<dim3(2, 8, 16), 256, 0, stream>>>(
      ap(XC, 1024), ap(XC, 1024), dn_w3, nullptr, nullptr, 256,
      P, nullptr, nullptr, 128, 64, 0, 65536);
  reduce_tanh<<<64, 256, 0, stream>>>(P, 65536, 16, dn_b3, (float*)d_out);
}

// Round 12
// 843.808 us; speedup vs baseline: 3.2070x; 3.2070x over previous
//
#include <hip/hip_runtime.h>

__device__ __forceinline__ float silu_f(float x) { return x / (1.f + __expf(-x)); }

// ================= double-buffered 64x64-tile GEMM core =================
// TG: A[m][k] = silu(tvec[m]*tw1[k] + tb0[k]).  BT: B stored [N][K].
// Bp pre-offset to slab rows for non-BT; kbase indexes A (and B when BT).
template <int TG, int BT>
__device__ __forceinline__ void dev_gemm(
    float (*As)[32][68], float (*Bs)[32][68],
    const float* __restrict__ Ap, int lda,
    const float* __restrict__ tw1, const float* __restrict__ tb0,
    const float* __restrict__ Bp, int ldb,
    float* __restrict__ Obase, int ldc,
    int kbase, int Kslab, long bm, long bn, float alpha) {
  const int tid = threadIdx.x;
  const int ar = tid >> 3, ak = (tid & 7) << 2;
  const int br = tid >> 4, bn4 = (tid & 15) << 2;
  const int ty = tid >> 4, tx = tid & 15;
  float acc[4][4] = {};
  float4 rA[2], rB[2], rW, rC;
  float tm0 = 0.f, tm1 = 0.f;
  if (TG) { tm0 = Ap[bm + ar]; tm1 = Ap[bm + ar + 32]; }
  auto loadA = [&](int k0) {
    int kg = kbase + k0 + ak;
    if (TG) {
      rW = *(const float4*)&tw1[kg];
      rC = *(const float4*)&tb0[kg];
    } else {
#pragma unroll
      for (int h = 0; h < 2; ++h)
        rA[h] = *(const float4*)&Ap[(bm + ar + h * 32) * (long)lda + kg];
    }
  };
  auto loadB = [&](int k0) {
    if (BT) {
#pragma unroll
      for (int h = 0; h < 2; ++h)
        rB[h] = *(const float4*)&Bp[(bn + ar + h * 32) * (long)ldb + kbase + k0 + ak];
    } else {
#pragma unroll
      for (int h = 0; h < 2; ++h)
        rB[h] = *(const float4*)&Bp[(long)(k0 + br + h * 16) * ldb + bn + bn4];
    }
  };
  auto store = [&](int buf) {
#pragma unroll
    for (int h = 0; h < 2; ++h) {
      int m = ar + h * 32;
      float4 av;
      if (TG) {
        float tm = h ? tm1 : tm0;
        av.x = silu_f(tm * rW.x + rC.x);
        av.y = silu_f(tm * rW.y + rC.y);
        av.z = silu_f(tm * rW.z + rC.z);
        av.w = silu_f(tm * rW.w + rC.w);
      } else {
        av = rA[h];
      }
      As[buf][ak + 0][m] = av.x; As[buf][ak + 1][m] = av.y;
      As[buf][ak + 2][m] = av.z; As[buf][ak + 3][m] = av.w;
    }
    if (BT) {
#pragma unroll
      for (int h = 0; h < 2; ++h) {
        int n = ar + h * 32;
        Bs[buf][ak + 0][n] = rB[h].x; Bs[buf][ak + 1][n] = rB[h].y;
        Bs[buf][ak + 2][n] = rB[h].z; Bs[buf][ak + 3][n] = rB[h].w;
      }
    } else {
#pragma unroll
      for (int h = 0; h < 2; ++h) *(float4*)&Bs[buf][br + h * 16][bn4] = rB[h];
    }
  };
  loadA(0); loadB(0);
  store(0);
  if (32 < Kslab) { loadA(32); loadB(32); }
  int cur = 0;
  for (int k0 = 0; k0 < Kslab; k0 += 32) {
    __syncthreads();
    if (k0 + 32 < Kslab) store(cur ^ 1);
    if (k0 + 64 < Kslab) { loadA(k0 + 64); loadB(k0 + 64); }
#pragma unroll
    for (int k = 0; k < 32; ++k) {
      float4 a4 = *(const float4*)&As[cur][k][ty << 2];
      float4 b4 = *(const float4*)&Bs[cur][k][tx << 2];
      float am[4] = {a4.x, a4.y, a4.z, a4.w};
      float bv[4] = {b4.x, b4.y, b4.z, b4.w};
#pragma unroll
      for (int i = 0; i < 4; ++i)
#pragma unroll
        for (int j = 0; j < 4; ++j) acc[i][j] = fmaf(am[i], bv[j], acc[i][j]);
    }
    cur ^= 1;
  }
  float* O = Obase + (bm + ty * 4) * (long)ldc + bn + tx * 4;
#pragma unroll
  for (int i = 0; i < 4; ++i) {
    float4 v = {alpha * acc[i][0], alpha * acc[i][1], alpha * acc[i][2],
                alpha * acc[i][3]};
    *(float4*)&O[(long)i * ldc] = v;
  }
}

// ---------------- last-block tile reduction: sum slabs + bias + act ----------------
template <int RACT>  // 0 none, 1 silu, 2 tanh
__device__ __forceinline__ void reduce_tile(
    const float* __restrict__ Pb, long slabMN, int nslab,
    const float* __restrict__ bias, float* __restrict__ cmp, int ldcmp,
    long bm, long bn, int ldc) {
  const int tid = threadIdx.x;
  const int r0 = (tid >> 4) * 4, c0 = (tid & 15) * 4;
  float4 bb = *(const float4*)&bias[bn + c0];
#pragma unroll
  for (int i = 0; i < 4; ++i) {
    long off = (bm + r0 + i) * (long)ldc + bn + c0;
    float4 s = *(const float4*)&Pb[off];
    for (int sl = 1; sl < nslab; ++sl) {
      float4 p = *(const float4*)&Pb[(long)sl * slabMN + off];
      s.x += p.x; s.y += p.y; s.z += p.z; s.w += p.w;
    }
    s.x += bb.x; s.y += bb.y; s.z += bb.z; s.w += bb.w;
    if (RACT == 1) {
      s.x = silu_f(s.x); s.y = silu_f(s.y); s.z = silu_f(s.z); s.w = silu_f(s.w);
    }
    if (RACT == 2) {
      s.x = tanhf(s.x); s.y = tanhf(s.y); s.z = tanhf(s.z); s.w = tanhf(s.w);
    }
    *(float4*)&cmp[(bm + r0 + i) * (long)ldcmp + bn + c0] = s;
  }
}

// ================= split-K GEMM with optional fused reduction =================
// grid(ntN, ntM, NPROB<<ls). zi = problem, s = K-slab. Slab (zi<<ls)+s of Parena.
// RACT>=0: per-tile counter; last-arriving block reduces nslab slabs -> cmp.
template <int NPROB, int T1GEN, int RACT>
__global__ __launch_bounds__(256) void gemm_f(
    const float* A0, const float* A1, const float* tw1, const float* tb0,
    int lda, const float* B0, const float* B1, int ldb,
    float* Parena, int ldc, long slabMN, int Kslab, int ls,
    unsigned* cnt, float* cmp, int ldcmp, const float* bias, int nslab) {
  __shared__ float As[2][32][68];
  __shared__ float Bs[2][32][68];
  __shared__ unsigned sflag;
  const int z = blockIdx.z;
  const int zi = (NPROB > 1) ? (z >> ls) : 0;
  const int s = (NPROB > 1) ? (z & ((1 << ls) - 1)) : z;
  const int kbase = s * Kslab;
  const long bm = blockIdx.y * 64, bn = blockIdx.x * 64;
  const float* Bsel = zi ? B1 : B0;
  const float* Bp = Bsel + (long)kbase * ldb;
  float* Obase = Parena + (long)((zi << ls) + s) * slabMN;
  if (T1GEN && zi == 1)
    dev_gemm<1, 0>(As, Bs, A1, 0, tw1, tb0, Bp, ldb, Obase, ldc, kbase, Kslab,
                   bm, bn, 1.f);
  else
    dev_gemm<0, 0>(As, Bs, zi ? A1 : A0, lda, nullptr, nullptr, Bp, ldb, Obase,
                   ldc, kbase, Kslab, bm, bn, 1.f);
  if (RACT >= 0) {
    __threadfence();
    __syncthreads();
    if (threadIdx.x == 0) {
      int tileId = blockIdx.y * gridDim.x + blockIdx.x;
      sflag = atomicAdd(&cnt[tileId], 1u);
    }
    __syncthreads();
    if (sflag == (unsigned)(nslab - 1)) {
      __threadfence();  // acquire: invalidate caches before reading other slabs
      reduce_tile<RACT>(Parena, slabMN, nslab, bias, cmp, ldcmp, bm, bn, ldc);
    }
  }
}

// ================= PRE1: qf/kf/vf + act1(s4, fused red) + Wx + Wt =================
__global__ __launch_bounds__(256) void pre1(
    const float* fid, const float* wq, const float* wk, const float* wv,
    const float* x_t, const float* fe_w1, const float* fe_b1,
    const float* fe_w2, const float* te_w2, const float* fp_w1,
    float* qf, float* kf, float* vf, float* P, float* SA, float* Wx, float* Wt,
    unsigned* cntA) {
  __shared__ float As[2][32][68];
  __shared__ float Bs[2][32][68];
  __shared__ unsigned sflag;
  const int w = blockIdx.x;
  if (w < 48) {  // qf/kf/vf: [128x512] = fid[128x128] @ w*, raw
    int prob = w >> 4, t = w & 15;
    const float* B = prob == 0 ? wq : (prob == 1 ? wk : wv);
    float* O = prob == 0 ? qf : (prob == 1 ? kf : vf);
    dev_gemm<0, 0>(As, Bs, fid, 128, nullptr, nullptr, B, 512, O, 512, 0, 128,
                   (t >> 3) * 64, (t & 7) * 64, 1.f);
  } else if (w < 304) {  // act1: x_t @ fe_w1, s4, fused silu(.+fe_b1) -> SA
    int w2 = w - 48, s = w2 & 3, t = w2 >> 2;
    long bm = (t >> 3) * 64, bn = (t & 7) * 64;
    dev_gemm<0, 0>(As, Bs, x_t, 128, nullptr, nullptr,
                   fe_w1 + (long)(s * 32) * 512, 512, P + (long)s * 262144, 512,
                   s * 32, 32, bm, bn, 1.f);
    __threadfence();
    __syncthreads();
    if (threadIdx.x == 0) sflag = atomicAdd(&cntA[t], 1u);
    __syncthreads();
    if (sflag == 3u) {
      __threadfence();
      reduce_tile<1>(P, 262144, 4, fe_b1, SA, 512, bm, bn, 512);
    }
  } else if (w < 368) {  // Wx = fe_w2 @ fp_w1[:512], K=512 full
    int t = w - 304;
    dev_gemm<0, 0>(As, Bs, fe_w2, 512, nullptr, nullptr, fp_w1, 512, Wx, 512,
                   0, 512, (t >> 3) * 64, (t & 7) * 64, 1.f);
  } else {  // Wt = te_w2 @ fp_w1[512:], K=512 full
    int t = w - 368;
    dev_gemm<0, 0>(As, Bs, te_w2, 512, nullptr, nullptr, fp_w1 + 512 * 512, 512,
                   Wt, 512, 0, 512, (t >> 3) * 64, (t & 7) * 64, 1.f);
  }
}

// ================= PRE2: M (BT gemm) + beff1 =================
__global__ __launch_bounds__(256) void pre2(
    const float* qf, const float* kf, float* Mb,
    const float* fp_b1, const float* fe_b2, const float* te_b2,
    const float* fp_w1, float* beff1) {
  __shared__ float As[2][32][68];
  __shared__ float Bs[2][32][68];
  const int w = blockIdx.x;
  if (w < 32) {  // M[h] = 0.00125 * qf_h @ kf_h^T  (64x... 128x128 per head)
    int h = w >> 2, t = w & 3;
    dev_gemm<0, 1>(As, Bs, qf + h * 64, 512, nullptr, nullptr, kf + h * 64, 512,
                   Mb + h * 128, 1024, 0, 64, (t >> 1) * 64, (t & 1) * 64,
                   0.00125f);
  } else {  // beff1[c] = fp_b1[c] + fe_b2@fp_w1[:512][c] + te_b2@fp_w1[512:][c]
    int c = (w - 32) * 256 + threadIdx.x;  // 512 cols
    float acc = fp_b1[c];
    for (int k = 0; k < 512; ++k) {
      acc += fe_b2[k] * fp_w1[(long)k * 512 + c];
      acc += te_b2[k] * fp_w1[(long)(512 + k) * 512 + c];
    }
    beff1[c] = acc;
  }
}

// ================= fused sparse attention + pooling (frozen, round-9) =================
__global__ __launch_bounds__(256) void attn_kernel(
    const float* __restrict__ PBq, const float* __restrict__ bq,
    const float* __restrict__ bv, const float* __restrict__ kf,
    const float* __restrict__ Mm, const float* __restrict__ vf,
    float* __restrict__ pool) {
  const int b = blockIdx.x, h = blockIdx.y;
  const int tid = threadIdx.x;
  __shared__ float uq[64];
  __shared__ float uls[128];
  __shared__ float wpart[4][128];
  __shared__ float wcol[128];
  __shared__ float ppart[2][64];

  if (tid < 64) {
    int c = h * 64 + tid;
    long o = (long)b * 512 + c;
    uq[tid] = PBq[o] + PBq[262144 + o] + PBq[524288 + o] + PBq[786432 + o] + bq[c];
  }
  __syncthreads();
  if (tid < 128) {
    const float* kr = kf + (long)tid * 512 + h * 64;
    float acc = 0.f;
#pragma unroll
    for (int d4 = 0; d4 < 16; ++d4) {
      float4 kv = *(const float4*)&kr[d4 * 4];
      acc += uq[d4 * 4] * kv.x + uq[d4 * 4 + 1] * kv.y +
             uq[d4 * 4 + 2] * kv.z + uq[d4 * 4 + 3] * kv.w;
    }
    uls[tid] = 0.0125f * acc;
  }
  __syncthreads();

  const int lane = tid & 63;
  const int wave = tid >> 6;
  const float u0 = uls[lane], u1 = uls[lane + 64];

  float blo = -0.5f, bhi = 0.5f;
#pragma unroll
  for (int it = 0; it < 11; ++it) {
    float mid = 0.5f * (blo + bhi);
    int n = __popcll(__ballot(u0 >= mid)) + __popcll(__ballot(u1 >= mid));
    bool ge = (n >= 64);
    blo = ge ? mid : blo;
    bhi = ge ? bhi : mid;
  }
  const float wlo = blo - 0.014f, whi = blo + 0.014f;

  float wc0 = 0.f, wc1 = 0.f;
  const float* Mh = Mm + h * 128;
  const int i0 = wave * 32;
  float a0r = Mh[(long)i0 * 1024 + lane];
  float a1r = Mh[(long)i0 * 1024 + lane + 64];
  float b0r = Mh[(long)(i0 + 1) * 1024 + lane];
  float b1r = Mh[(long)(i0 + 1) * 1024 + lane + 64];
  for (int r = 0; r < 32; r += 2) {
    float TA0 = u0 + a0r, TA1 = u1 + a1r;
    float TB0 = u0 + b0r, TB1 = u1 + b1r;
    if (r < 30) {
      a0r = Mh[(long)(i0 + r + 2) * 1024 + lane];
      a1r = Mh[(long)(i0 + r + 2) * 1024 + lane + 64];
      b0r = Mh[(long)(i0 + r + 3) * 1024 + lane];
      b1r = Mh[(long)(i0 + r + 3) * 1024 + lane + 64];
    }
    float loA = wlo, hiA = whi, loB = wlo, hiB = whi;
#pragma unroll
    for (int it = 0; it < 5; ++it) {
      float midA = 0.5f * (loA + hiA), midB = 0.5f * (loB + hiB);
      int nA = __popcll(__ballot(TA0 >= midA)) + __popcll(__ballot(TA1 >= midA));
      int nB = __popcll(__ballot(TB0 >= midB)) + __popcll(__ballot(TB1 >= midB));
      bool gA = (nA >= 64), gB = (nB >= 64);
      loA = gA ? midA : loA; hiA = gA ? hiA : midA;
      loB = gB ? midB : loB; hiB = gB ? hiB : midB;
    }
    float pA0 = (TA0 >= loA) ? __expf(TA0 - loA) : 0.f;
    float pA1 = (TA1 >= loA) ? __expf(TA1 - loA) : 0.f;
    float pB0 = (TB0 >= loB) ? __expf(TB0 - loB) : 0.f;
    float pB1 = (TB1 >= loB) ? __expf(TB1 - loB) : 0.f;
    float sA = pA0 + pA1, sB = pB0 + pB1;
#pragma unroll
    for (int d = 1; d < 64; d <<= 1) {
      sA += __shfl_xor(sA, d);
      sB += __shfl_xor(sB, d);
    }
    float ivA = 1.f / sA, ivB = 1.f / sB;
    wc0 += pA0 * ivA + pB0 * ivB;
    wc1 += pA1 * ivA + pB1 * ivB;
  }
  wpart[wave][lane] = wc0;
  wpart[wave][lane + 64] = wc1;
  __syncthreads();
  if (tid < 128) {
    wcol[tid] = (wpart[0][tid] + wpart[1][tid] + wpart[2][tid] + wpart[3][tid]) *
                (1.f / 128.f);
  }
  __syncthreads();
  if (wave < 2) {
    int j0 = wave * 64;
    const float* vfp = vf + h * 64 + lane;
    float acc = 0.f;
#pragma unroll 8
    for (int jj = 0; jj < 64; ++jj) acc += wcol[j0 + jj] * vfp[(long)(j0 + jj) * 512];
    ppart[wave][lane] = acc;
  }
  __syncthreads();
  if (tid < 64) {
    int d = tid;
    int c = h * 64 + d;
    long o = (long)b * 512 + c;
    long vb0 = 4 * 262144;
    float v = PBq[vb0 + o] + PBq[vb0 + 262144 + o] + PBq[vb0 + 524288 + o] +
              PBq[vb0 + 786432 + o] + bv[c];
    pool[o] = 0.1f * (ppart[0][d] + ppart[1][d]) + v;
  }
}

// LayerNorm over 512 cols (8 partial slabs + bias), eps 1e-5, affine
__global__ __launch_bounds__(256) void ln_kernel(const float* __restrict__ P,
                                                 const float* __restrict__ bias,
                                                 const float* __restrict__ g,
                                                 const float* __restrict__ bb,
                                                 float* __restrict__ Y) {
  int row = blockIdx.x;
  int tid = threadIdx.x;
  long o0 = (long)row * 512 + tid;
  long o1 = o0 + 256;
  float v0 = bias[tid], v1 = bias[tid + 256];
#pragma unroll
  for (int s = 0; s < 8; ++s) {
    v0 += P[(long)s * 262144 + o0];
    v1 += P[(long)s * 262144 + o1];
  }
  float s = v0 + v1;
#pragma unroll
  for (int d = 1; d < 64; d <<= 1) s += __shfl_xor(s, d);
  __shared__ float r1[4], r2[4];
  if ((tid & 63) == 0) r1[tid >> 6] = s;
  __syncthreads();
  float mean = (r1[0] + r1[1] + r1[2] + r1[3]) * (1.f / 512.f);
  float d0 = v0 - mean, d1 = v1 - mean;
  float q = d0 * d0 + d1 * d1;
#pragma unroll
  for (int d = 1; d < 64; d <<= 1) q += __shfl_xor(q, d);
  if ((tid & 63) == 0) r2[tid >> 6] = q;
  __syncthreads();
  float var = (r2[0] + r2[1] + r2[2] + r2[3]) * (1.f / 512.f);
  float inv = rsqrtf(var + 1e-5f);
  Y[(long)row * 512 + tid] = d0 * inv * g[tid] + bb[tid];
  Y[(long)row * 512 + tid + 256] = d1 * inv * g[tid + 256] + bb[tid + 256];
}

// ================= host =================
extern "C" void kernel_launch(void* const* d_in, const int* in_sizes, int n_in,
                              void* d_out, int out_size, void* d_ws, size_t ws_size,
                              hipStream_t stream) {
  const float* x_t = (const float*)d_in[0];
  const float* t_in = (const float*)d_in[1];
  const float* te_w1 = (const float*)d_in[2];
  const float* te_b1 = (const float*)d_in[3];
  const float* te_w2 = (const float*)d_in[4];
  const float* te_b2 = (const float*)d_in[5];
  const float* fe_w1 = (const float*)d_in[6];
  const float* fe_b1 = (const float*)d_in[7];
  const float* fe_w2 = (const float*)d_in[8];
  const float* fe_b2 = (const float*)d_in[9];
  const float* fp_w1 = (const float*)d_in[10];
  const float* fp_b1 = (const float*)d_in[11];
  const float* fp_w2 = (const float*)d_in[12];
  const float* fp_b2 = (const float*)d_in[13];
  const float* fp_w3 = (const float*)d_in[14];
  const float* fp_b3 = (const float*)d_in[15];
  const float* fid = (const float*)d_in[16];
  const float* wq = (const float*)d_in[17];
  const float* bq = (const float*)d_in[18];
  const float* wk = (const float*)d_in[19];
  // d_in[20]=bk cancels (row-constant in softmax) -> unused
  const float* wv = (const float*)d_in[21];
  const float* bv = (const float*)d_in[22];
  const float* wo = (const float*)d_in[23];
  const float* bo = (const float*)d_in[24];
  const float* gp_w1 = (const float*)d_in[25];
  const float* gp_b1 = (const float*)d_in[26];
  const float* gp_w2 = (const float*)d_in[27];
  const float* gp_b2 = (const float*)d_in[28];
  const float* ln_g = (const float*)d_in[29];
  const float* ln_b = (const float*)d_in[30];
  const float* dn_w1 = (const float*)d_in[31];
  const float* dn_b1 = (const float*)d_in[32];
  const float* dn_w2 = (const float*)d_in[33];
  const float* dn_b2 = (const float*)d_in[34];
  const float* dn_w3 = (const float*)d_in[35];
  const float* dn_b3 = (const float*)d_in[36];

  // Layout (floats) — total 16.26 MiB (< proven 17.25 MiB):
  float* W = (float*)d_ws;
  float* P   = W;                  // 2,097,152 slab arena
  float* XC  = W + 2097152;        // 524,288
  float* SB  = W + 2621440;        // 262,144  (h1s -> pool)     \ XC2 = SB..SC
  float* SC  = W + 2883584;        // 262,144  (h2s -> g1s)      /
  float* XC2 = SB;                 // 524,288 overlay (live only r2->out)
  float* SA  = W + 3145728;        // 262,144  (act1s -> base -> ln out)
  float* Wx  = W + 3407872;        // 262,144
  float* Wt  = W + 3670016;        // 262,144
  float* qf  = W + 3932160;        // 65,536
  float* kf  = W + 3997696;        // 65,536
  float* vf  = W + 4063232;        // 65,536
  float* Mb  = W + 4128768;        // 131,072
  float* beff1 = W + 4259840;      // 1,024 (512 used)
  unsigned* cnt = (unsigned*)(W + 4260864);  // 1,024 slots (720 used)

  unsigned* cA  = cnt;         // act1 64
  unsigned* cH1 = cnt + 64;    // h1 64
  unsigned* cH2 = cnt + 128;   // h2 64
  unsigned* cB  = cnt + 192;   // base 64
  unsigned* cG1 = cnt + 256;   // g1 64
  unsigned* cG2 = cnt + 320;   // g2 128
  unsigned* cR1 = cnt + 448;   // r1 128
  unsigned* cR2 = cnt + 576;   // r2 128
  unsigned* cO  = cnt + 704;   // out 16

  hipMemsetAsync(cnt, 0, 4096, stream);

  // PRE1: qf/kf/vf + act1 (fused silu+fe_b1 -> SA) + Wx + Wt
  pre1<<<432, 256, 0, stream>>>(fid, wq, wk, wv, x_t, fe_w1, fe_b1, fe_w2,
                                te_w2, fp_w1, qf, kf, vf, P, SA, Wx, Wt, cA);
  // PRE2: M + beff1
  pre2<<<34, 256, 0, stream>>>(qf, kf, Mb, fp_b1, fe_b2, te_b2, fp_w1, beff1);
  // h1 = silu(SA@Wx + tgen@Wt + beff1): 2-prob s4 -> 8 slabs -> SB
  gemm_f<2, 1, 1><<<dim3(8, 8, 8), 256, 0, stream>>>(
      SA, t_in, te_w1, te_b1, 512, Wx, Wt, 512, P, 512, 262144, 128, 2,
      cH1, SB, 512, beff1, 8);
  // h2 = silu(SB@fp_w2 + fp_b2): s8 -> SC
  gemm_f<1, 0, 1><<<dim3(8, 8, 8), 256, 0, stream>>>(
      SB, nullptr, nullptr, nullptr, 512, fp_w2, nullptr, 512, P, 512, 262144,
      64, 0, cH2, SC, 512, fp_b2, 8);
  // base = SC@fp_w3 + fp_b3: s8 -> SA
  gemm_f<1, 0, 0><<<dim3(8, 8, 8), 256, 0, stream>>>(
      SC, nullptr, nullptr, nullptr, 512, fp_w3, nullptr, 512, P, 512, 262144,
      64, 0, cB, SA, 512, fp_b3, 8);
  // qb & vb: SA@{wq,wv} s4 each -> P slabs 0..7 (no reduction; attn consumes)
  gemm_f<2, 0, -1><<<dim3(8, 8, 8), 256, 0, stream>>>(
      SA, SA, nullptr, nullptr, 512, wq, wv, 512, P, 512, 262144, 128, 2,
      nullptr, nullptr, 0, nullptr, 0);
  // attention -> pool (SB)
  attn_kernel<<<dim3(512, 8), 256, 0, stream>>>(P, bq, bv, kf, Mb, vf, SB);
  // g1 = SB@wo + bo: s8 -> SC
  gemm_f<1, 0, 0><<<dim3(8, 8, 8), 256, 0, stream>>>(
      SB, nullptr, nullptr, nullptr, 512, wo, nullptr, 512, P, 512, 262144,
      64, 0, cG1, SC, 512, bo, 8);
  // g2 = silu(SC@gp_w1 + gp_b1): N=1024 s4 -> XC
  gemm_f<1, 0, 1><<<dim3(16, 8, 4), 256, 0, stream>>>(
      SC, nullptr, nullptr, nullptr, 512, gp_w1, nullptr, 1024, P, 1024, 524288,
      128, 0, cG2, XC, 1024, gp_b1, 4);
  // g3 = XC@gp_w2: K=1024 s8 -> slabs (ln consumes)
  gemm_f<1, 0, -1><<<dim3(8, 8, 8), 256, 0, stream>>>(
      XC, nullptr, nullptr, nullptr, 1024, gp_w2, nullptr, 512, P, 512, 262144,
      128, 0, nullptr, nullptr, 0, nullptr, 0);
  // ln(sum8 + gp_b2) -> SA
  ln_kernel<<<512, 256, 0, stream>>>(P, gp_b2, ln_g, ln_b, SA);
  // r1 = silu(SA@dn_w1 + dn_b1): N=1024 s4 -> XC
  gemm_f<1, 0, 1><<<dim3(16, 8, 4), 256, 0, stream>>>(
      SA, nullptr, nullptr, nullptr, 512, dn_w1, nullptr, 1024, P, 1024, 524288,
      128, 0, cR1, XC, 1024, dn_b1, 4);
  // r2 = silu(XC@dn_w2 + dn_b2): K=1024 N=1024 s4 -> XC2
  gemm_f<1, 0, 1><<<dim3(16, 8, 4), 256, 0, stream>>>(
      XC, nullptr, nullptr, nullptr, 1024, dn_w2, nullptr, 1024, P, 1024, 524288,
      256, 0, cR2, XC2, 1024, dn_b2, 4);
  // out = tanh(XC2@dn_w3[:, :128] + dn_b3): s16 -> d_out
  gemm_f<1, 0, 2><<<dim3(2, 8, 16), 256, 0, stream>>>(
      XC2, nullptr, nullptr, nullptr, 1024, dn_w3, nullptr, 256, P, 128, 65536,
      64, 0, cO, (float*)d_out, 128, dn_b3, 16);
}

// Round 13
// 282.619 us; speedup vs baseline: 9.5751x; 2.9857x over previous
//
#include <hip/hip_runtime.h>

__device__ __forceinline__ float silu_f(float x) { return x / (1.f + __expf(-x)); }

// ================= double-buffered 64x64-tile GEMM device core =================
// TG: A[m][k] = silu(tvec[m]*tw1[k] + tb0[k]).  BT: B stored [N][K].
// Bp pre-offset to slab rows for non-BT; kbase indexes A (and B when BT).
template <int TG, int BT>
__device__ __forceinline__ void dev_gemm(
    float (*As)[32][68], float (*Bs)[32][68],
    const float* __restrict__ Ap, int lda,
    const float* __restrict__ tw1, const float* __restrict__ tb0,
    const float* __restrict__ Bp, int ldb,
    float* __restrict__ Obase, int ldc,
    int kbase, int Kslab, long bm, long bn, float alpha) {
  const int tid = threadIdx.x;
  const int ar = tid >> 3, ak = (tid & 7) << 2;
  const int br = tid >> 4, bn4 = (tid & 15) << 2;
  const int ty = tid >> 4, tx = tid & 15;
  float acc[4][4] = {};
  float4 rA[2], rB[2], rW, rC;
  float tm0 = 0.f, tm1 = 0.f;
  if (TG) { tm0 = Ap[bm + ar]; tm1 = Ap[bm + ar + 32]; }
  auto loadA = [&](int k0) {
    int kg = kbase + k0 + ak;
    if (TG) {
      rW = *(const float4*)&tw1[kg];
      rC = *(const float4*)&tb0[kg];
    } else {
#pragma unroll
      for (int h = 0; h < 2; ++h)
        rA[h] = *(const float4*)&Ap[(bm + ar + h * 32) * (long)lda + kg];
    }
  };
  auto loadB = [&](int k0) {
    if (BT) {
#pragma unroll
      for (int h = 0; h < 2; ++h)
        rB[h] = *(const float4*)&Bp[(bn + ar + h * 32) * (long)ldb + kbase + k0 + ak];
    } else {
#pragma unroll
      for (int h = 0; h < 2; ++h)
        rB[h] = *(const float4*)&Bp[(long)(k0 + br + h * 16) * ldb + bn + bn4];
    }
  };
  auto store = [&](int buf) {
#pragma unroll
    for (int h = 0; h < 2; ++h) {
      int m = ar + h * 32;
      float4 av;
      if (TG) {
        float tm = h ? tm1 : tm0;
        av.x = silu_f(tm * rW.x + rC.x);
        av.y = silu_f(tm * rW.y + rC.y);
        av.z = silu_f(tm * rW.z + rC.z);
        av.w = silu_f(tm * rW.w + rC.w);
      } else {
        av = rA[h];
      }
      As[buf][ak + 0][m] = av.x; As[buf][ak + 1][m] = av.y;
      As[buf][ak + 2][m] = av.z; As[buf][ak + 3][m] = av.w;
    }
    if (BT) {
#pragma unroll
      for (int h = 0; h < 2; ++h) {
        int n = ar + h * 32;
        Bs[buf][ak + 0][n] = rB[h].x; Bs[buf][ak + 1][n] = rB[h].y;
        Bs[buf][ak + 2][n] = rB[h].z; Bs[buf][ak + 3][n] = rB[h].w;
      }
    } else {
#pragma unroll
      for (int h = 0; h < 2; ++h) *(float4*)&Bs[buf][br + h * 16][bn4] = rB[h];
    }
  };
  loadA(0); loadB(0);
  store(0);
  if (32 < Kslab) { loadA(32); loadB(32); }
  int cur = 0;
  for (int k0 = 0; k0 < Kslab; k0 += 32) {
    __syncthreads();
    if (k0 + 32 < Kslab) store(cur ^ 1);
    if (k0 + 64 < Kslab) { loadA(k0 + 64); loadB(k0 + 64); }
#pragma unroll
    for (int k = 0; k < 32; ++k) {
      float4 a4 = *(const float4*)&As[cur][k][ty << 2];
      float4 b4 = *(const float4*)&Bs[cur][k][tx << 2];
      float am[4] = {a4.x, a4.y, a4.z, a4.w};
      float bv[4] = {b4.x, b4.y, b4.z, b4.w};
#pragma unroll
      for (int i = 0; i < 4; ++i)
#pragma unroll
        for (int j = 0; j < 4; ++j) acc[i][j] = fmaf(am[i], bv[j], acc[i][j]);
    }
    cur ^= 1;
  }
  float* O = Obase + (bm + ty * 4) * (long)ldc + bn + tx * 4;
#pragma unroll
  for (int i = 0; i < 4; ++i) {
    float4 v = {alpha * acc[i][0], alpha * acc[i][1], alpha * acc[i][2],
                alpha * acc[i][3]};
    *(float4*)&O[(long)i * ldc] = v;
  }
}

// ================= multi-problem split-K partial GEMM (round-9 proven) =================
struct AOp {
  const float* P;
  const float* w1;
  const float* b0;
  int lda;
  int tgen;
};

template <int NPROB, int T1GEN>
__global__ __launch_bounds__(256) void gemm_p(
    AOp a0, AOp a1,
    const float* __restrict__ B0, const float* __restrict__ B1,
    const float* __restrict__ B2, int ldb,
    float* __restrict__ O0, float* __restrict__ O1, float* __restrict__ O2,
    int ldc, int Kslab, int ls, long slabMN) {
  __shared__ float As[2][32][68];
  __shared__ float Bs[2][32][68];
  const int z = blockIdx.z;
  const int zi = (NPROB > 1) ? (z >> ls) : 0;
  const int s = (NPROB > 1) ? (z & ((1 << ls) - 1)) : z;
  const AOp a = (NPROB > 1 && zi == 1) ? a1 : a0;
  const float* Bp = ((NPROB > 2 && zi == 2) ? B2 : (zi == 1) ? B1 : B0)
                    + (long)(s * Kslab) * ldb;
  float* Obase = ((NPROB > 2 && zi == 2) ? O2 : (zi == 1) ? O1 : O0)
                 + (long)s * slabMN;
  const int kbase = s * Kslab;
  const long bm = blockIdx.y * 64, bn = blockIdx.x * 64;
  if (T1GEN && a.tgen)
    dev_gemm<1, 0>(As, Bs, a.P, 0, a.w1, a.b0, Bp, ldb, Obase, ldc, kbase,
                   Kslab, bm, bn, 1.f);
  else
    dev_gemm<0, 0>(As, Bs, a.P, a.lda, nullptr, nullptr, Bp, ldb, Obase, ldc,
                   kbase, Kslab, bm, bn, 1.f);
}

// ================= PRE1: qf/kf/vf + act1 partials + Wx + Wt (all independent) ======
__global__ __launch_bounds__(256) void pre1(
    const float* fid, const float* wq, const float* wk, const float* wv,
    const float* x_t, const float* fe_w1,
    const float* fe_w2, const float* te_w2, const float* fp_w1,
    float* qf, float* kf, float* vf, float* P, float* Wx, float* Wt) {
  __shared__ float As[2][32][68];
  __shared__ float Bs[2][32][68];
  const int w = blockIdx.x;
  if (w < 48) {  // qf/kf/vf = fid[128x128] @ w*, raw
    int prob = w >> 4, t = w & 15;
    const float* B = prob == 0 ? wq : (prob == 1 ? wk : wv);
    float* O = prob == 0 ? qf : (prob == 1 ? kf : vf);
    dev_gemm<0, 0>(As, Bs, fid, 128, nullptr, nullptr, B, 512, O, 512, 0, 128,
                   (t >> 3) * 64, (t & 7) * 64, 1.f);
  } else if (w < 304) {  // act1: x_t @ fe_w1, s4 raw partials -> P
    int w2 = w - 48, s = w2 & 3, t = w2 >> 2;
    dev_gemm<0, 0>(As, Bs, x_t, 128, nullptr, nullptr,
                   fe_w1 + (long)(s * 32) * 512, 512, P + (long)s * 262144, 512,
                   s * 32, 32, (t >> 3) * 64, (t & 7) * 64, 1.f);
  } else if (w < 368) {  // Wx = fe_w2 @ fp_w1[:512]
    int t = w - 304;
    dev_gemm<0, 0>(As, Bs, fe_w2, 512, nullptr, nullptr, fp_w1, 512, Wx, 512,
                   0, 512, (t >> 3) * 64, (t & 7) * 64, 1.f);
  } else {  // Wt = te_w2 @ fp_w1[512:]
    int t = w - 368;
    dev_gemm<0, 0>(As, Bs, te_w2, 512, nullptr, nullptr,
                   fp_w1 + (long)512 * 512, 512, Wt, 512, 0, 512,
                   (t >> 3) * 64, (t & 7) * 64, 1.f);
  }
}

// ================= PRE2: M + beff1 + act1 sumk (all depend only on PRE1) ==========
__global__ __launch_bounds__(256) void pre2(
    const float* qf, const float* kf, float* Mb,
    const float* fp_b1, const float* fe_b2, const float* te_b2,
    const float* fp_w1, float* beff1,
    const float* P, const float* fe_b1, float* SA) {
  __shared__ float As[2][32][68];
  __shared__ float Bs[2][32][68];
  __shared__ float red[4][64];
  const int w = blockIdx.x;
  const int tid = threadIdx.x;
  if (w < 32) {  // M[h] = 0.00125 * qf_h @ kf_h^T
    int h = w >> 2, t = w & 3;
    dev_gemm<0, 1>(As, Bs, qf + h * 64, 512, nullptr, nullptr, kf + h * 64, 512,
                   Mb + h * 128, 1024, 0, 64, (t >> 1) * 64, (t & 1) * 64,
                   0.00125f);
  } else if (w < 40) {  // beff1 = fp_b1 + fe_b2@fp_w1[:512] + te_b2@fp_w1[512:]
    int w2 = w - 32;                 // 0..7, 64 cols each
    int c = w2 * 64 + (tid & 63);
    int ks = tid >> 6;               // 0..3
    float acc = 0.f;
    for (int k = ks * 128; k < ks * 128 + 128; ++k)
      acc += fe_b2[k] * fp_w1[(long)k * 512 + c] +
             te_b2[k] * fp_w1[(long)(512 + k) * 512 + c];
    red[ks][tid & 63] = acc;
    __syncthreads();
    if (tid < 64)
      beff1[w2 * 64 + tid] =
          fp_b1[w2 * 64 + tid] + red[0][tid] + red[1][tid] + red[2][tid] + red[3][tid];
  } else {  // SA = silu(sum4(act1 partials) + fe_b1)
    int idx0 = (w - 40) * 256 + tid;  // 64 blocks -> 16384 threads
    for (int q = 0; q < 4; ++q) {
      long i4 = (long)(idx0 + q * 16384) << 2;
      float4 s = *(const float4*)&P[i4];
#pragma unroll
      for (int si = 1; si < 4; ++si) {
        float4 p = *(const float4*)&P[(long)si * 262144 + i4];
        s.x += p.x; s.y += p.y; s.z += p.z; s.w += p.w;
      }
      int c = (int)i4 & 511;
      float4 bb = *(const float4*)&fe_b1[c];
      s.x = silu_f(s.x + bb.x); s.y = silu_f(s.y + bb.y);
      s.z = silu_f(s.z + bb.z); s.w = silu_f(s.w + bb.w);
      *(float4*)&SA[i4] = s;
    }
  }
}

// ================= slab-sum + bias + act -> compact =================
template <int NS, int ACT>
__global__ __launch_bounds__(256) void sumk(
    const float* __restrict__ P, long slabMN,
    const float* __restrict__ b0, int cmask, float* __restrict__ out) {
  int i4 = (blockIdx.x * 256 + threadIdx.x) << 2;
  float4 s = *(const float4*)&P[i4];
#pragma unroll
  for (int si = 1; si < NS; ++si) {
    float4 p = *(const float4*)&P[(long)si * slabMN + i4];
    s.x += p.x; s.y += p.y; s.z += p.z; s.w += p.w;
  }
  int c = i4 & cmask;
  float4 bb = *(const float4*)&b0[c];
  s.x += bb.x; s.y += bb.y; s.z += bb.z; s.w += bb.w;
  if (ACT == 1) {
    s.x = silu_f(s.x); s.y = silu_f(s.y); s.z = silu_f(s.z); s.w = silu_f(s.w);
  }
  *(float4*)&out[i4] = s;
}

// reduce split-K partials: C = tanh(sum16 + bias)
__global__ __launch_bounds__(256) void reduce_tanh(
    const float* __restrict__ P, int slabMN, int nslab,
    const float* __restrict__ bias, float* __restrict__ C) {
  int i4 = (blockIdx.x * 256 + threadIdx.x) << 2;
  float4 s = *(const float4*)&P[i4];
  for (int si = 1; si < nslab; ++si) {
    float4 p = *(const float4*)&P[(long)si * slabMN + i4];
    s.x += p.x; s.y += p.y; s.z += p.z; s.w += p.w;
  }
  int c = i4 & 127;
  float4 v = {tanhf(s.x + bias[c]), tanhf(s.y + bias[c + 1]),
              tanhf(s.z + bias[c + 2]), tanhf(s.w + bias[c + 3])};
  *(float4*)&C[i4] = v;
}

// ================= fused sparse attention + pooling (frozen, round-9) =============
__global__ __launch_bounds__(256) void attn_kernel(
    const float* __restrict__ PBq, const float* __restrict__ bq,
    const float* __restrict__ bv, const float* __restrict__ kf,
    const float* __restrict__ Mm, const float* __restrict__ vf,
    float* __restrict__ pool) {
  const int b = blockIdx.x, h = blockIdx.y;
  const int tid = threadIdx.x;
  __shared__ float uq[64];
  __shared__ float uls[128];
  __shared__ float wpart[4][128];
  __shared__ float wcol[128];
  __shared__ float ppart[2][64];

  if (tid < 64) {
    int c = h * 64 + tid;
    long o = (long)b * 512 + c;
    uq[tid] = PBq[o] + PBq[262144 + o] + PBq[524288 + o] + PBq[786432 + o] + bq[c];
  }
  __syncthreads();
  if (tid < 128) {
    const float* kr = kf + (long)tid * 512 + h * 64;
    float acc = 0.f;
#pragma unroll
    for (int d4 = 0; d4 < 16; ++d4) {
      float4 kv = *(const float4*)&kr[d4 * 4];
      acc += uq[d4 * 4] * kv.x + uq[d4 * 4 + 1] * kv.y +
             uq[d4 * 4 + 2] * kv.z + uq[d4 * 4 + 3] * kv.w;
    }
    uls[tid] = 0.0125f * acc;
  }
  __syncthreads();

  const int lane = tid & 63;
  const int wave = tid >> 6;
  const float u0 = uls[lane], u1 = uls[lane + 64];

  float blo = -0.5f, bhi = 0.5f;
#pragma unroll
  for (int it = 0; it < 11; ++it) {
    float mid = 0.5f * (blo + bhi);
    int n = __popcll(__ballot(u0 >= mid)) + __popcll(__ballot(u1 >= mid));
    bool ge = (n >= 64);
    blo = ge ? mid : blo;
    bhi = ge ? bhi : mid;
  }
  const float wlo = blo - 0.014f, whi = blo + 0.014f;

  float wc0 = 0.f, wc1 = 0.f;
  const float* Mh = Mm + h * 128;
  const int i0 = wave * 32;
  float a0r = Mh[(long)i0 * 1024 + lane];
  float a1r = Mh[(long)i0 * 1024 + lane + 64];
  float b0r = Mh[(long)(i0 + 1) * 1024 + lane];
  float b1r = Mh[(long)(i0 + 1) * 1024 + lane + 64];
  for (int r = 0; r < 32; r += 2) {
    float TA0 = u0 + a0r, TA1 = u1 + a1r;
    float TB0 = u0 + b0r, TB1 = u1 + b1r;
    if (r < 30) {
      a0r = Mh[(long)(i0 + r + 2) * 1024 + lane];
      a1r = Mh[(long)(i0 + r + 2) * 1024 + lane + 64];
      b0r = Mh[(long)(i0 + r + 3) * 1024 + lane];
      b1r = Mh[(long)(i0 + r + 3) * 1024 + lane + 64];
    }
    float loA = wlo, hiA = whi, loB = wlo, hiB = whi;
#pragma unroll
    for (int it = 0; it < 5; ++it) {
      float midA = 0.5f * (loA + hiA), midB = 0.5f * (loB + hiB);
      int nA = __popcll(__ballot(TA0 >= midA)) + __popcll(__ballot(TA1 >= midA));
      int nB = __popcll(__ballot(TB0 >= midB)) + __popcll(__ballot(TB1 >= midB));
      bool gA = (nA >= 64), gB = (nB >= 64);
      loA = gA ? midA : loA; hiA = gA ? hiA : midA;
      loB = gB ? midB : loB; hiB = gB ? hiB : midB;
    }
    float pA0 = (TA0 >= loA) ? __expf(TA0 - loA) : 0.f;
    float pA1 = (TA1 >= loA) ? __expf(TA1 - loA) : 0.f;
    float pB0 = (TB0 >= loB) ? __expf(TB0 - loB) : 0.f;
    float pB1 = (TB1 >= loB) ? __expf(TB1 - loB) : 0.f;
    float sA = pA0 + pA1, sB = pB0 + pB1;
#pragma unroll
    for (int d = 1; d < 64; d <<= 1) {
      sA += __shfl_xor(sA, d);
      sB += __shfl_xor(sB, d);
    }
    float ivA = 1.f / sA, ivB = 1.f / sB;
    wc0 += pA0 * ivA + pB0 * ivB;
    wc1 += pA1 * ivA + pB1 * ivB;
  }
  wpart[wave][lane] = wc0;
  wpart[wave][lane + 64] = wc1;
  __syncthreads();
  if (tid < 128) {
    wcol[tid] = (wpart[0][tid] + wpart[1][tid] + wpart[2][tid] + wpart[3][tid]) *
                (1.f / 128.f);
  }
  __syncthreads();
  if (wave < 2) {
    int j0 = wave * 64;
    const float* vfp = vf + h * 64 + lane;
    float acc = 0.f;
#pragma unroll 8
    for (int jj = 0; jj < 64; ++jj) acc += wcol[j0 + jj] * vfp[(long)(j0 + jj) * 512];
    ppart[wave][lane] = acc;
  }
  __syncthreads();
  if (tid < 64) {
    int d = tid;
    int c = h * 64 + d;
    long o = (long)b * 512 + c;
    long vb0 = 4 * 262144;
    float v = PBq[vb0 + o] + PBq[vb0 + 262144 + o] + PBq[vb0 + 524288 + o] +
              PBq[vb0 + 786432 + o] + bv[c];
    pool[o] = 0.1f * (ppart[0][d] + ppart[1][d]) + v;
  }
}

// LayerNorm over 512 cols (8 partial slabs + bias), eps 1e-5, affine
__global__ __launch_bounds__(256) void ln_kernel(const float* __restrict__ P,
                                                 const float* __restrict__ bias,
                                                 const float* __restrict__ g,
                                                 const float* __restrict__ bb,
                                                 float* __restrict__ Y) {
  int row = blockIdx.x;
  int tid = threadIdx.x;
  long o0 = (long)row * 512 + tid;
  long o1 = o0 + 256;
  float v0 = bias[tid], v1 = bias[tid + 256];
#pragma unroll
  for (int s = 0; s < 8; ++s) {
    v0 += P[(long)s * 262144 + o0];
    v1 += P[(long)s * 262144 + o1];
  }
  float s = v0 + v1;
#pragma unroll
  for (int d = 1; d < 64; d <<= 1) s += __shfl_xor(s, d);
  __shared__ float r1[4], r2[4];
  if ((tid & 63) == 0) r1[tid >> 6] = s;
  __syncthreads();
  float mean = (r1[0] + r1[1] + r1[2] + r1[3]) * (1.f / 512.f);
  float d0 = v0 - mean, d1 = v1 - mean;
  float q = d0 * d0 + d1 * d1;
#pragma unroll
  for (int d = 1; d < 64; d <<= 1) q += __shfl_xor(q, d);
  if ((tid & 63) == 0) r2[tid >> 6] = q;
  __syncthreads();
  float var = (r2[0] + r2[1] + r2[2] + r2[3]) * (1.f / 512.f);
  float inv = rsqrtf(var + 1e-5f);
  Y[(long)row * 512 + tid] = d0 * inv * g[tid] + bb[tid];
  Y[(long)row * 512 + tid + 256] = d1 * inv * g[tid + 256] + bb[tid + 256];
}

// ================= host =================
extern "C" void kernel_launch(void* const* d_in, const int* in_sizes, int n_in,
                              void* d_out, int out_size, void* d_ws, size_t ws_size,
                              hipStream_t stream) {
  const float* x_t = (const float*)d_in[0];
  const float* t_in = (const float*)d_in[1];
  const float* te_w1 = (const float*)d_in[2];
  const float* te_b1 = (const float*)d_in[3];
  const float* te_w2 = (const float*)d_in[4];
  const float* te_b2 = (const float*)d_in[5];
  const float* fe_w1 = (const float*)d_in[6];
  const float* fe_b1 = (const float*)d_in[7];
  const float* fe_w2 = (const float*)d_in[8];
  const float* fe_b2 = (const float*)d_in[9];
  const float* fp_w1 = (const float*)d_in[10];
  const float* fp_b1 = (const float*)d_in[11];
  const float* fp_w2 = (const float*)d_in[12];
  const float* fp_b2 = (const float*)d_in[13];
  const float* fp_w3 = (const float*)d_in[14];
  const float* fp_b3 = (const float*)d_in[15];
  const float* fid = (const float*)d_in[16];
  const float* wq = (const float*)d_in[17];
  const float* bq = (const float*)d_in[18];
  const float* wk = (const float*)d_in[19];
  // d_in[20]=bk cancels (row-constant in softmax) -> unused
  const float* wv = (const float*)d_in[21];
  const float* bv = (const float*)d_in[22];
  const float* wo = (const float*)d_in[23];
  const float* bo = (const float*)d_in[24];
  const float* gp_w1 = (const float*)d_in[25];
  const float* gp_b1 = (const float*)d_in[26];
  const float* gp_w2 = (const float*)d_in[27];
  const float* gp_b2 = (const float*)d_in[28];
  const float* ln_g = (const float*)d_in[29];
  const float* ln_b = (const float*)d_in[30];
  const float* dn_w1 = (const float*)d_in[31];
  const float* dn_b1 = (const float*)d_in[32];
  const float* dn_w2 = (const float*)d_in[33];
  const float* dn_b2 = (const float*)d_in[34];
  const float* dn_w3 = (const float*)d_in[35];
  const float* dn_b3 = (const float*)d_in[36];

  // Layout (floats) — 3,998,720 = 15.25 MiB (< proven-available):
  float* W = (float*)d_ws;
  float* P   = W;                  // 2,097,152 slab arena
  float* XC  = W + 2097152;        // 524,288
  float* SB  = W + 2621440;        // 262,144  \ XC2 overlays SB+SA (both dead by r2)
  float* SA  = W + 2883584;        // 262,144  /
  float* XC2 = W + 2621440;        // 524,288 overlay
  float* Wx  = W + 3145728;        // 262,144
  float* Wt  = W + 3407872;        // 262,144
  float* qf  = W + 3670016;        // 65,536
  float* kf  = W + 3735552;        // 65,536
  float* vf  = W + 3801088;        // 65,536
  float* Mb  = W + 3866624;        // 131,072
  float* beff1 = W + 3997696;      // 1,024 (512 used)

  auto ap = [](const float* Pm, int lda) {
    AOp a; a.P = Pm; a.w1 = nullptr; a.b0 = nullptr; a.lda = lda; a.tgen = 0;
    return a;
  };

  // PRE1: qf/kf/vf + act1 partials + Wx + Wt (all independent)
  pre1<<<432, 256, 0, stream>>>(fid, wq, wk, wv, x_t, fe_w1, fe_w2, te_w2,
                                fp_w1, qf, kf, vf, P, Wx, Wt);
  // PRE2: M + beff1 + act1-sumk -> SA
  pre2<<<104, 256, 0, stream>>>(qf, kf, Mb, fp_b1, fe_b2, te_b2, fp_w1, beff1,
                                P, fe_b1, SA);
  // h1 = silu(SA@Wx + tgen(t)@Wt + beff1): 2-prob s4 -> 8 slabs
  {
    AOp a1; a1.P = t_in; a1.w1 = te_w1; a1.b0 = te_b1; a1.lda = 0; a1.tgen = 1;
    gemm_p<2, 1><<<dim3(8, 8, 8), 256, 0, stream>>>(
        ap(SA, 512), a1, Wx, Wt, nullptr, 512,
        P, P + 1048576, nullptr, 512, 128, 2, 262144);
  }
  sumk<8, 1><<<256, 256, 0, stream>>>(P, 262144, beff1, 511, SB);
  // h2 = silu(SB@fp_w2 + fp_b2): s8
  gemm_p<1, 0><<<dim3(8, 8, 8), 256, 0, stream>>>(
      ap(SB, 512), ap(SB, 512), fp_w2, nullptr, nullptr, 512,
      P, nullptr, nullptr, 512, 64, 0, 262144);
  sumk<8, 1><<<256, 256, 0, stream>>>(P, 262144, fp_b2, 511, SA);
  // base = SA@fp_w3 + fp_b3: s8
  gemm_p<1, 0><<<dim3(8, 8, 8), 256, 0, stream>>>(
      ap(SA, 512), ap(SA, 512), fp_w3, nullptr, nullptr, 512,
      P, nullptr, nullptr, 512, 64, 0, 262144);
  sumk<8, 0><<<256, 256, 0, stream>>>(P, 262144, fp_b3, 511, SB);
  // qb & vb: SB@{wq,wv} s4 each -> P slabs 0..7 (attn consumes raw)
  gemm_p<2, 0><<<dim3(8, 8, 8), 256, 0, stream>>>(
      ap(SB, 512), ap(SB, 512), wq, wv, nullptr, 512,
      P, P + 1048576, nullptr, 512, 128, 2, 262144);
  // attention -> pool (SA)
  attn_kernel<<<dim3(512, 8), 256, 0, stream>>>(P, bq, bv, kf, Mb, vf, SA);
  // g1 = SA@wo + bo: s8
  gemm_p<1, 0><<<dim3(8, 8, 8), 256, 0, stream>>>(
      ap(SA, 512), ap(SA, 512), wo, nullptr, nullptr, 512,
      P, nullptr, nullptr, 512, 64, 0, 262144);
  sumk<8, 0><<<256, 256, 0, stream>>>(P, 262144, bo, 511, SB);
  // g2 = silu(SB@gp_w1 + gp_b1): N=1024 s4
  gemm_p<1, 0><<<dim3(16, 8, 4), 256, 0, stream>>>(
      ap(SB, 512), ap(SB, 512), gp_w1, nullptr, nullptr, 1024,
      P, nullptr, nullptr, 1024, 128, 0, 524288);
  sumk<4, 1><<<512, 256, 0, stream>>>(P, 524288, gp_b1, 1023, XC);
  // g3 = XC@gp_w2: K=1024 s8 (ln consumes slabs)
  gemm_p<1, 0><<<dim3(8, 8, 8), 256, 0, stream>>>(
      ap(XC, 1024), ap(XC, 1024), gp_w2, nullptr, nullptr, 512,
      P, nullptr, nullptr, 512, 128, 0, 262144);
  // ln(sum8 + gp_b2) -> SA
  ln_kernel<<<512, 256, 0, stream>>>(P, gp_b2, ln_g, ln_b, SA);
  // r1 = silu(SA@dn_w1 + dn_b1): N=1024 s4
  gemm_p<1, 0><<<dim3(16, 8, 4), 256, 0, stream>>>(
      ap(SA, 512), ap(SA, 512), dn_w1, nullptr, nullptr, 1024,
      P, nullptr, nullptr, 1024, 128, 0, 524288);
  sumk<4, 1><<<512, 256, 0, stream>>>(P, 524288, dn_b1, 1023, XC);
  // r2 = silu(XC@dn_w2 + dn_b2): K=1024 N=1024 s4
  gemm_p<1, 0><<<dim3(16, 8, 4), 256, 0, stream>>>(
      ap(XC, 1024), ap(XC, 1024), dn_w2, nullptr, nullptr, 1024,
      P, nullptr, nullptr, 1024, 256, 0, 524288);
  sumk<4, 1><<<512, 256, 0, stream>>>(P, 524288, dn_b2, 1023, XC2);
  // out = XC2@dn_w3[:, :128]: s16
  gemm_p<1, 0><<<dim3(2, 8, 16), 256, 0, stream>>>(
      ap(XC2, 1024), ap(XC2, 1024), dn_w3, nullptr, nullptr, 256,
      P, nullptr, nullptr, 128, 64, 0, 65536);
  // tanh(sum16 + dn_b3) -> d_out (f32)
  reduce_tanh<<<64, 256, 0, stream>>>(P, 65536, 16, dn_b3, (float*)d_out);
}

// Round 14
// 265.758 us; speedup vs baseline: 10.1826x; 1.0634x over previous
//
#include <hip/hip_runtime.h>

__device__ __forceinline__ float silu_f(float x) { return x / (1.f + __expf(-x)); }

// ================= double-buffered 64x64-tile GEMM device core =================
// TG: A[m][k] = silu(tvec[m]*tw1[k] + tb0[k]).  BT: B stored [N][K].
// Convention: caller pre-offsets Bp for non-BT slabs; kbase indexes A (and B when BT).
template <int TG, int BT>
__device__ __forceinline__ void dev_gemm(
    float (*As)[32][68], float (*Bs)[32][68],
    const float* __restrict__ Ap, int lda,
    const float* __restrict__ tw1, const float* __restrict__ tb0,
    const float* __restrict__ Bp, int ldb,
    float* __restrict__ Obase, int ldc,
    int kbase, int Kslab, long bm, long bn, float alpha) {
  const int tid = threadIdx.x;
  const int ar = tid >> 3, ak = (tid & 7) << 2;
  const int br = tid >> 4, bn4 = (tid & 15) << 2;
  const int ty = tid >> 4, tx = tid & 15;
  float acc[4][4] = {};
  float4 rA[2], rB[2], rW, rC;
  float tm0 = 0.f, tm1 = 0.f;
  if (TG) { tm0 = Ap[bm + ar]; tm1 = Ap[bm + ar + 32]; }
  auto loadA = [&](int k0) {
    int kg = kbase + k0 + ak;
    if (TG) {
      rW = *(const float4*)&tw1[kg];
      rC = *(const float4*)&tb0[kg];
    } else {
#pragma unroll
      for (int h = 0; h < 2; ++h)
        rA[h] = *(const float4*)&Ap[(bm + ar + h * 32) * (long)lda + kg];
    }
  };
  auto loadB = [&](int k0) {
    if (BT) {
#pragma unroll
      for (int h = 0; h < 2; ++h)
        rB[h] = *(const float4*)&Bp[(bn + ar + h * 32) * (long)ldb + kbase + k0 + ak];
    } else {
#pragma unroll
      for (int h = 0; h < 2; ++h)
        rB[h] = *(const float4*)&Bp[(long)(k0 + br + h * 16) * ldb + bn + bn4];
    }
  };
  auto store = [&](int buf) {
#pragma unroll
    for (int h = 0; h < 2; ++h) {
      int m = ar + h * 32;
      float4 av;
      if (TG) {
        float tm = h ? tm1 : tm0;
        av.x = silu_f(tm * rW.x + rC.x);
        av.y = silu_f(tm * rW.y + rC.y);
        av.z = silu_f(tm * rW.z + rC.z);
        av.w = silu_f(tm * rW.w + rC.w);
      } else {
        av = rA[h];
      }
      As[buf][ak + 0][m] = av.x; As[buf][ak + 1][m] = av.y;
      As[buf][ak + 2][m] = av.z; As[buf][ak + 3][m] = av.w;
    }
    if (BT) {
#pragma unroll
      for (int h = 0; h < 2; ++h) {
        int n = ar + h * 32;
        Bs[buf][ak + 0][n] = rB[h].x; Bs[buf][ak + 1][n] = rB[h].y;
        Bs[buf][ak + 2][n] = rB[h].z; Bs[buf][ak + 3][n] = rB[h].w;
      }
    } else {
#pragma unroll
      for (int h = 0; h < 2; ++h) *(float4*)&Bs[buf][br + h * 16][bn4] = rB[h];
    }
  };
  loadA(0); loadB(0);
  store(0);
  if (32 < Kslab) { loadA(32); loadB(32); }
  int cur = 0;
  for (int k0 = 0; k0 < Kslab; k0 += 32) {
    __syncthreads();
    if (k0 + 32 < Kslab) store(cur ^ 1);
    if (k0 + 64 < Kslab) { loadA(k0 + 64); loadB(k0 + 64); }
#pragma unroll
    for (int k = 0; k < 32; ++k) {
      float4 a4 = *(const float4*)&As[cur][k][ty << 2];
      float4 b4 = *(const float4*)&Bs[cur][k][tx << 2];
      float am[4] = {a4.x, a4.y, a4.z, a4.w};
      float bv[4] = {b4.x, b4.y, b4.z, b4.w};
#pragma unroll
      for (int i = 0; i < 4; ++i)
#pragma unroll
        for (int j = 0; j < 4; ++j) acc[i][j] = fmaf(am[i], bv[j], acc[i][j]);
    }
    cur ^= 1;
  }
  float* O = Obase + (bm + ty * 4) * (long)ldc + bn + tx * 4;
#pragma unroll
  for (int i = 0; i < 4; ++i) {
    float4 v = {alpha * acc[i][0], alpha * acc[i][1], alpha * acc[i][2],
                alpha * acc[i][3]};
    *(float4*)&O[(long)i * ldc] = v;
  }
}

// ================= multi-problem split-K partial GEMM =================
struct AOp {
  const float* P;
  const float* w1;
  const float* b0;
  int lda;
  int tgen;
};

template <int NPROB, int T1GEN>
__global__ __launch_bounds__(256) void gemm_p(
    AOp a0, AOp a1,
    const float* __restrict__ B0, const float* __restrict__ B1,
    const float* __restrict__ B2, int ldb,
    float* __restrict__ O0, float* __restrict__ O1, float* __restrict__ O2,
    int ldc, int Kslab, int ls, long slabMN) {
  __shared__ float As[2][32][68];
  __shared__ float Bs[2][32][68];
  const int z = blockIdx.z;
  const int zi = (NPROB > 1) ? (z >> ls) : 0;
  const int s = (NPROB > 1) ? (z & ((1 << ls) - 1)) : z;
  const AOp a = (NPROB > 1 && zi == 1) ? a1 : a0;
  const float* Bp = ((NPROB > 2 && zi == 2) ? B2 : (zi == 1) ? B1 : B0)
                    + (long)(s * Kslab) * ldb;
  float* Obase = ((NPROB > 2 && zi == 2) ? O2 : (zi == 1) ? O1 : O0)
                 + (long)s * slabMN;
  const int kbase = s * Kslab;
  const long bm = blockIdx.y * 64, bn = blockIdx.x * 64;
  if (T1GEN && a.tgen)
    dev_gemm<1, 0>(As, Bs, a.P, 0, a.w1, a.b0, Bp, ldb, Obase, ldc, kbase,
                   Kslab, bm, bn, 1.f);
  else
    dev_gemm<0, 0>(As, Bs, a.P, a.lda, nullptr, nullptr, Bp, ldb, Obase, ldc,
                   kbase, Kslab, bm, bn, 1.f);
}

// ================= PRE1: all input-only work in one launch =================
struct P1 {
  const float *fid, *wq, *wk, *wv, *x_t, *fe_w1, *fe_w2, *te_w2, *fp_w1, *fp_w3,
      *wo, *gp_w1;
  const float *fp_b1, *fe_b2, *te_b2, *fp_b3, *bq, *bv, *bo, *gp_b1;
  float *qf, *kf, *vf, *P, *Wx, *Wt, *Wq2, *Wv2, *Wg, *beff1, *bq2, *bv2, *bg2;
};

__global__ __launch_bounds__(256) void pre1(P1 p) {
  __shared__ float As[2][32][68];
  __shared__ float Bs[2][32][68];
  __shared__ float red[4][64];
  const int w = blockIdx.x;
  const int tid = threadIdx.x;
  if (w < 48) {  // qf/kf/vf = fid[128x128] @ w*
    int prob = w >> 4, t = w & 15;
    const float* B = prob == 0 ? p.wq : (prob == 1 ? p.wk : p.wv);
    float* O = prob == 0 ? p.qf : (prob == 1 ? p.kf : p.vf);
    dev_gemm<0, 0>(As, Bs, p.fid, 128, nullptr, nullptr, B, 512, O, 512, 0, 128,
                   (t >> 3) * 64, (t & 7) * 64, 1.f);
  } else if (w < 304) {  // act1: x_t @ fe_w1, s4 raw partials -> P slabs 0-3
    int w2 = w - 48, s = w2 & 3, t = w2 >> 2;
    dev_gemm<0, 0>(As, Bs, p.x_t, 128, nullptr, nullptr,
                   p.fe_w1 + (long)(s * 32) * 512, 512, p.P + (long)s * 262144,
                   512, s * 32, 32, (t >> 3) * 64, (t & 7) * 64, 1.f);
  } else if (w < 368) {  // Wx = fe_w2 @ fp_w1[:512]
    int t = w - 304;
    dev_gemm<0, 0>(As, Bs, p.fe_w2, 512, nullptr, nullptr, p.fp_w1, 512, p.Wx,
                   512, 0, 512, (t >> 3) * 64, (t & 7) * 64, 1.f);
  } else if (w < 432) {  // Wt = te_w2 @ fp_w1[512:]
    int t = w - 368;
    dev_gemm<0, 0>(As, Bs, p.te_w2, 512, nullptr, nullptr,
                   p.fp_w1 + (long)512 * 512, 512, p.Wt, 512, 0, 512,
                   (t >> 3) * 64, (t & 7) * 64, 1.f);
  } else if (w < 496) {  // Wq2 = fp_w3 @ wq
    int t = w - 432;
    dev_gemm<0, 0>(As, Bs, p.fp_w3, 512, nullptr, nullptr, p.wq, 512, p.Wq2,
                   512, 0, 512, (t >> 3) * 64, (t & 7) * 64, 1.f);
  } else if (w < 560) {  // Wv2 = fp_w3 @ wv
    int t = w - 496;
    dev_gemm<0, 0>(As, Bs, p.fp_w3, 512, nullptr, nullptr, p.wv, 512, p.Wv2,
                   512, 0, 512, (t >> 3) * 64, (t & 7) * 64, 1.f);
  } else if (w < 688) {  // Wg = wo @ gp_w1  [512x1024]
    int t = w - 560;
    dev_gemm<0, 0>(As, Bs, p.wo, 512, nullptr, nullptr, p.gp_w1, 1024, p.Wg,
                   1024, 0, 512, (t >> 4) * 64, (t & 15) * 64, 1.f);
  } else {  // bias-fold vectors
    int c64 = tid & 63, ks = tid >> 6;
    if (w < 696) {  // beff1 = fp_b1 + fe_b2@fp_w1[:512] + te_b2@fp_w1[512:]
      int c = (w - 688) * 64 + c64;
      float acc = 0.f;
      for (int k = ks * 128; k < ks * 128 + 128; ++k)
        acc += p.fe_b2[k] * p.fp_w1[(long)k * 512 + c] +
               p.te_b2[k] * p.fp_w1[(long)(512 + k) * 512 + c];
      red[ks][c64] = acc;
      __syncthreads();
      if (tid < 64)
        p.beff1[c - c64 + tid] = p.fp_b1[c - c64 + tid] + red[0][tid] +
                                 red[1][tid] + red[2][tid] + red[3][tid];
    } else if (w < 704) {  // bq2 = bq + fp_b3 @ wq
      int c = (w - 696) * 64 + c64;
      float acc = 0.f;
      for (int k = ks * 128; k < ks * 128 + 128; ++k)
        acc += p.fp_b3[k] * p.wq[(long)k * 512 + c];
      red[ks][c64] = acc;
      __syncthreads();
      if (tid < 64)
        p.bq2[c - c64 + tid] = p.bq[c - c64 + tid] + red[0][tid] + red[1][tid] +
                               red[2][tid] + red[3][tid];
    } else if (w < 712) {  // bv2 = bv + fp_b3 @ wv
      int c = (w - 704) * 64 + c64;
      float acc = 0.f;
      for (int k = ks * 128; k < ks * 128 + 128; ++k)
        acc += p.fp_b3[k] * p.wv[(long)k * 512 + c];
      red[ks][c64] = acc;
      __syncthreads();
      if (tid < 64)
        p.bv2[c - c64 + tid] = p.bv[c - c64 + tid] + red[0][tid] + red[1][tid] +
                               red[2][tid] + red[3][tid];
    } else {  // bg2 = gp_b1 + bo @ gp_w1  (1024 cols)
      int c = (w - 712) * 64 + c64;
      float acc = 0.f;
      for (int k = ks * 128; k < ks * 128 + 128; ++k)
        acc += p.bo[k] * p.gp_w1[(long)k * 1024 + c];
      red[ks][c64] = acc;
      __syncthreads();
      if (tid < 64)
        p.bg2[c - c64 + tid] = p.gp_b1[c - c64 + tid] + red[0][tid] +
                               red[1][tid] + red[2][tid] + red[3][tid];
    }
  }
}

// ================= PRE2: M + act1-sumk =================
__global__ __launch_bounds__(256) void pre2(
    const float* qf, const float* kf, float* Mb,
    const float* P, const float* fe_b1, float* SAc) {
  __shared__ float As[2][32][68];
  __shared__ float Bs[2][32][68];
  const int w = blockIdx.x;
  const int tid = threadIdx.x;
  if (w < 32) {  // M[h] = 0.00125 * qf_h @ kf_h^T
    int h = w >> 2, t = w & 3;
    dev_gemm<0, 1>(As, Bs, qf + h * 64, 512, nullptr, nullptr, kf + h * 64, 512,
                   Mb + h * 128, 1024, 0, 64, (t >> 1) * 64, (t & 1) * 64,
                   0.00125f);
  } else {  // SAc = silu(sum4(act1 partials) + fe_b1)
    int idx0 = (w - 32) * 256 + tid;  // 64 blocks
    for (int q = 0; q < 4; ++q) {
      long i4 = (long)(idx0 + q * 16384) << 2;
      float4 s = *(const float4*)&P[i4];
#pragma unroll
      for (int si = 1; si < 4; ++si) {
        float4 pp = *(const float4*)&P[(long)si * 262144 + i4];
        s.x += pp.x; s.y += pp.y; s.z += pp.z; s.w += pp.w;
      }
      int c = (int)i4 & 511;
      float4 bb = *(const float4*)&fe_b1[c];
      s.x = silu_f(s.x + bb.x); s.y = silu_f(s.y + bb.y);
      s.z = silu_f(s.z + bb.z); s.w = silu_f(s.w + bb.w);
      *(float4*)&SAc[i4] = s;
    }
  }
}

// ================= slab-sum + bias + act -> compact =================
template <int NS, int ACT>
__global__ __launch_bounds__(256) void sumk(
    const float* __restrict__ P, long slabMN,
    const float* __restrict__ b0, int cmask, float* __restrict__ out) {
  int i4 = (blockIdx.x * 256 + threadIdx.x) << 2;
  float4 s = *(const float4*)&P[i4];
#pragma unroll
  for (int si = 1; si < NS; ++si) {
    float4 p = *(const float4*)&P[(long)si * slabMN + i4];
    s.x += p.x; s.y += p.y; s.z += p.z; s.w += p.w;
  }
  int c = i4 & cmask;
  float4 bb = *(const float4*)&b0[c];
  s.x += bb.x; s.y += bb.y; s.z += bb.z; s.w += bb.w;
  if (ACT == 1) {
    s.x = silu_f(s.x); s.y = silu_f(s.y); s.z = silu_f(s.z); s.w = silu_f(s.w);
  }
  *(float4*)&out[i4] = s;
}

// reduce split-K partials: C = tanh(sum16 + bias)
__global__ __launch_bounds__(256) void reduce_tanh(
    const float* __restrict__ P, int slabMN, int nslab,
    const float* __restrict__ bias, float* __restrict__ C) {
  int i4 = (blockIdx.x * 256 + threadIdx.x) << 2;
  float4 s = *(const float4*)&P[i4];
  for (int si = 1; si < nslab; ++si) {
    float4 p = *(const float4*)&P[(long)si * slabMN + i4];
    s.x += p.x; s.y += p.y; s.z += p.z; s.w += p.w;
  }
  int c = i4 & 127;
  float4 v = {tanhf(s.x + bias[c]), tanhf(s.y + bias[c + 1]),
              tanhf(s.z + bias[c + 2]), tanhf(s.w + bias[c + 3])};
  *(float4*)&C[i4] = v;
}

// ================= fused sparse attention + pooling (r9 logic, 2-slab qb/vb) ======
__global__ __launch_bounds__(256) void attn_kernel(
    const float* __restrict__ PBq,  // qb slabs @0,262144; vb slabs @524288,786432
    const float* __restrict__ bq,
    const float* __restrict__ bv,
    const float* __restrict__ kf,   // raw [128][512]
    const float* __restrict__ Mm,   // [128][1024] (alpha 0.00125 applied)
    const float* __restrict__ vf,   // raw [128][512]
    float* __restrict__ pool) {
  const int b = blockIdx.x, h = blockIdx.y;
  const int tid = threadIdx.x;
  __shared__ float uq[64];
  __shared__ float uls[128];
  __shared__ float wpart[4][128];
  __shared__ float wcol[128];
  __shared__ float ppart[2][64];

  if (tid < 64) {
    int c = h * 64 + tid;
    long o = (long)b * 512 + c;
    uq[tid] = PBq[o] + PBq[262144 + o] + bq[c];
  }
  __syncthreads();
  if (tid < 128) {
    const float* kr = kf + (long)tid * 512 + h * 64;
    float acc = 0.f;
#pragma unroll
    for (int d4 = 0; d4 < 16; ++d4) {
      float4 kv = *(const float4*)&kr[d4 * 4];
      acc += uq[d4 * 4] * kv.x + uq[d4 * 4 + 1] * kv.y +
             uq[d4 * 4 + 2] * kv.z + uq[d4 * 4 + 3] * kv.w;
    }
    uls[tid] = 0.0125f * acc;
  }
  __syncthreads();

  const int lane = tid & 63;
  const int wave = tid >> 6;
  const float u0 = uls[lane], u1 = uls[lane + 64];

  float blo = -0.5f, bhi = 0.5f;
#pragma unroll
  for (int it = 0; it < 11; ++it) {
    float mid = 0.5f * (blo + bhi);
    int n = __popcll(__ballot(u0 >= mid)) + __popcll(__ballot(u1 >= mid));
    bool ge = (n >= 64);
    blo = ge ? mid : blo;
    bhi = ge ? bhi : mid;
  }
  const float wlo = blo - 0.014f, whi = blo + 0.014f;

  float wc0 = 0.f, wc1 = 0.f;
  const float* Mh = Mm + h * 128;
  const int i0 = wave * 32;
  float a0r = Mh[(long)i0 * 1024 + lane];
  float a1r = Mh[(long)i0 * 1024 + lane + 64];
  float b0r = Mh[(long)(i0 + 1) * 1024 + lane];
  float b1r = Mh[(long)(i0 + 1) * 1024 + lane + 64];
  for (int r = 0; r < 32; r += 2) {
    float TA0 = u0 + a0r, TA1 = u1 + a1r;
    float TB0 = u0 + b0r, TB1 = u1 + b1r;
    if (r < 30) {
      a0r = Mh[(long)(i0 + r + 2) * 1024 + lane];
      a1r = Mh[(long)(i0 + r + 2) * 1024 + lane + 64];
      b0r = Mh[(long)(i0 + r + 3) * 1024 + lane];
      b1r = Mh[(long)(i0 + r + 3) * 1024 + lane + 64];
    }
    float loA = wlo, hiA = whi, loB = wlo, hiB = whi;
#pragma unroll
    for (int it = 0; it < 5; ++it) {
      float midA = 0.5f * (loA + hiA), midB = 0.5f * (loB + hiB);
      int nA = __popcll(__ballot(TA0 >= midA)) + __popcll(__ballot(TA1 >= midA));
      int nB = __popcll(__ballot(TB0 >= midB)) + __popcll(__ballot(TB1 >= midB));
      bool gA = (nA >= 64), gB = (nB >= 64);
      loA = gA ? midA : loA; hiA = gA ? hiA : midA;
      loB = gB ? midB : loB; hiB = gB ? hiB : midB;
    }
    float pA0 = (TA0 >= loA) ? __expf(TA0 - loA) : 0.f;
    float pA1 = (TA1 >= loA) ? __expf(TA1 - loA) : 0.f;
    float pB0 = (TB0 >= loB) ? __expf(TB0 - loB) : 0.f;
    float pB1 = (TB1 >= loB) ? __expf(TB1 - loB) : 0.f;
    float sA = pA0 + pA1, sB = pB0 + pB1;
#pragma unroll
    for (int d = 1; d < 64; d <<= 1) {
      sA += __shfl_xor(sA, d);
      sB += __shfl_xor(sB, d);
    }
    float ivA = 1.f / sA, ivB = 1.f / sB;
    wc0 += pA0 * ivA + pB0 * ivB;
    wc1 += pA1 * ivA + pB1 * ivB;
  }
  wpart[wave][lane] = wc0;
  wpart[wave][lane + 64] = wc1;
  __syncthreads();
  if (tid < 128) {
    wcol[tid] = (wpart[0][tid] + wpart[1][tid] + wpart[2][tid] + wpart[3][tid]) *
                (1.f / 128.f);
  }
  __syncthreads();
  if (wave < 2) {
    int j0 = wave * 64;
    const float* vfp = vf + h * 64 + lane;
    float acc = 0.f;
#pragma unroll 8
    for (int jj = 0; jj < 64; ++jj) acc += wcol[j0 + jj] * vfp[(long)(j0 + jj) * 512];
    ppart[wave][lane] = acc;
  }
  __syncthreads();
  if (tid < 64) {
    int d = tid;
    int c = h * 64 + d;
    long o = (long)b * 512 + c;
    float v = PBq[524288 + o] + PBq[786432 + o] + bv[c];
    pool[o] = 0.1f * (ppart[0][d] + ppart[1][d]) + v;
  }
}

// LayerNorm over 512 cols (4 partial slabs + bias), eps 1e-5, affine
__global__ __launch_bounds__(256) void ln_kernel(const float* __restrict__ P,
                                                 const float* __restrict__ bias,
                                                 const float* __restrict__ g,
                                                 const float* __restrict__ bb,
                                                 float* __restrict__ Y) {
  int row = blockIdx.x;
  int tid = threadIdx.x;
  long o0 = (long)row * 512 + tid;
  long o1 = o0 + 256;
  float v0 = bias[tid], v1 = bias[tid + 256];
#pragma unroll
  for (int s = 0; s < 4; ++s) {
    v0 += P[(long)s * 262144 + o0];
    v1 += P[(long)s * 262144 + o1];
  }
  float s = v0 + v1;
#pragma unroll
  for (int d = 1; d < 64; d <<= 1) s += __shfl_xor(s, d);
  __shared__ float r1[4], r2[4];
  if ((tid & 63) == 0) r1[tid >> 6] = s;
  __syncthreads();
  float mean = (r1[0] + r1[1] + r1[2] + r1[3]) * (1.f / 512.f);
  float d0 = v0 - mean, d1 = v1 - mean;
  float q = d0 * d0 + d1 * d1;
#pragma unroll
  for (int d = 1; d < 64; d <<= 1) q += __shfl_xor(q, d);
  if ((tid & 63) == 0) r2[tid >> 6] = q;
  __syncthreads();
  float var = (r2[0] + r2[1] + r2[2] + r2[3]) * (1.f / 512.f);
  float inv = rsqrtf(var + 1e-5f);
  Y[(long)row * 512 + tid] = d0 * inv * g[tid] + bb[tid];
  Y[(long)row * 512 + tid + 256] = d1 * inv * g[tid + 256] + bb[tid + 256];
}

// ================= host =================
extern "C" void kernel_launch(void* const* d_in, const int* in_sizes, int n_in,
                              void* d_out, int out_size, void* d_ws, size_t ws_size,
                              hipStream_t stream) {
  const float* x_t = (const float*)d_in[0];
  const float* t_in = (const float*)d_in[1];
  const float* te_w1 = (const float*)d_in[2];
  const float* te_b1 = (const float*)d_in[3];
  const float* te_w2 = (const float*)d_in[4];
  const float* te_b2 = (const float*)d_in[5];
  const float* fe_w1 = (const float*)d_in[6];
  const float* fe_b1 = (const float*)d_in[7];
  const float* fe_w2 = (const float*)d_in[8];
  const float* fe_b2 = (const float*)d_in[9];
  const float* fp_w1 = (const float*)d_in[10];
  const float* fp_b1 = (const float*)d_in[11];
  const float* fp_w2 = (const float*)d_in[12];
  const float* fp_b2 = (const float*)d_in[13];
  const float* fp_w3 = (const float*)d_in[14];
  const float* fp_b3 = (const float*)d_in[15];
  const float* fid = (const float*)d_in[16];
  const float* wq = (const float*)d_in[17];
  const float* bq = (const float*)d_in[18];
  const float* wk = (const float*)d_in[19];
  // d_in[20]=bk cancels (row-constant in softmax) -> unused
  const float* wv = (const float*)d_in[21];
  const float* bv = (const float*)d_in[22];
  const float* wo = (const float*)d_in[23];
  const float* bo = (const float*)d_in[24];
  const float* gp_w1 = (const float*)d_in[25];
  const float* gp_b1 = (const float*)d_in[26];
  const float* gp_w2 = (const float*)d_in[27];
  const float* gp_b2 = (const float*)d_in[28];
  const float* ln_g = (const float*)d_in[29];
  const float* ln_b = (const float*)d_in[30];
  const float* dn_w1 = (const float*)d_in[31];
  const float* dn_b1 = (const float*)d_in[32];
  const float* dn_w2 = (const float*)d_in[33];
  const float* dn_b2 = (const float*)d_in[34];
  const float* dn_w3 = (const float*)d_in[35];
  const float* dn_b3 = (const float*)d_in[36];

  // Layout (floats) — 4,000,256 = 15.26 MiB (< proven 17.25 MiB):
  // Arena A (2M): lower 1M = split-K partials; upper 1M = compacts (overlaid).
  float* A = (float*)d_ws;
  float* U0 = A + 1048576;         // 262144: act1c -> h2c
  float* U1 = A + 1310720;         // 262144: h1c -> pool
  float* XC = A + 1048576;         // 524288 view: g2c (after pool dead)
  float* LNOUT = A + 1572864;      // 262144
  float* Wx = A + 2097152;         // 262144 \ XC2 overlay (dead after h1)
  float* Wt = A + 2359296;         // 262144 /
  float* XC2 = A + 2097152;        // 524288
  float* Wq2 = A + 2621440;        // 262144 \ XC3 overlay (dead after qbvb)
  float* Wv2 = A + 2883584;        // 262144 /
  float* XC3 = A + 2621440;        // 524288
  float* Wg = A + 3145728;         // 524288
  float* qf = A + 3670016;         // 65536
  float* kf = A + 3735552;         // 65536
  float* vf = A + 3801088;         // 65536
  float* Mb = A + 3866624;         // 131072
  float* beff1 = A + 3997696;      // 512
  float* bq2 = A + 3998208;        // 512
  float* bv2 = A + 3998720;        // 512
  float* bg2 = A + 3999232;        // 1024

  auto ap = [](const float* Pm, int lda) {
    AOp a; a.P = Pm; a.w1 = nullptr; a.b0 = nullptr; a.lda = lda; a.tgen = 0;
    return a;
  };

  // PRE1: everything that depends only on inputs
  P1 p1;
  p1.fid = fid; p1.wq = wq; p1.wk = wk; p1.wv = wv; p1.x_t = x_t;
  p1.fe_w1 = fe_w1; p1.fe_w2 = fe_w2; p1.te_w2 = te_w2; p1.fp_w1 = fp_w1;
  p1.fp_w3 = fp_w3; p1.wo = wo; p1.gp_w1 = gp_w1;
  p1.fp_b1 = fp_b1; p1.fe_b2 = fe_b2; p1.te_b2 = te_b2; p1.fp_b3 = fp_b3;
  p1.bq = bq; p1.bv = bv; p1.bo = bo; p1.gp_b1 = gp_b1;
  p1.qf = qf; p1.kf = kf; p1.vf = vf; p1.P = A; p1.Wx = Wx; p1.Wt = Wt;
  p1.Wq2 = Wq2; p1.Wv2 = Wv2; p1.Wg = Wg; p1.beff1 = beff1; p1.bq2 = bq2;
  p1.bv2 = bv2; p1.bg2 = bg2;
  pre1<<<728, 256, 0, stream>>>(p1);
  // PRE2: M + act1-sumk -> U0
  pre2<<<96, 256, 0, stream>>>(qf, kf, Mb, A, fe_b1, U0);
  // h1 = silu(U0@Wx + tgen(t)@Wt + beff1): 2-prob s2 -> slabs L0-L3
  {
    AOp a1; a1.P = t_in; a1.w1 = te_w1; a1.b0 = te_b1; a1.lda = 0; a1.tgen = 1;
    gemm_p<2, 1><<<dim3(8, 8, 4), 256, 0, stream>>>(
        ap(U0, 512), a1, Wx, Wt, nullptr, 512,
        A, A + 524288, nullptr, 512, 256, 1, 262144);
  }
  sumk<4, 1><<<256, 256, 0, stream>>>(A, 262144, beff1, 511, U1);
  // h2 = silu(U1@fp_w2 + fp_b2): s4 -> L0-L3
  gemm_p<1, 0><<<dim3(8, 8, 4), 256, 0, stream>>>(
      ap(U1, 512), ap(U1, 512), fp_w2, nullptr, nullptr, 512,
      A, nullptr, nullptr, 512, 128, 0, 262144);
  sumk<4, 1><<<256, 256, 0, stream>>>(A, 262144, fp_b2, 511, U0);
  // qb & vb (base folded): U0@{Wq2,Wv2}, s2 each -> L0-L3
  gemm_p<2, 0><<<dim3(8, 8, 4), 256, 0, stream>>>(
      ap(U0, 512), ap(U0, 512), Wq2, Wv2, nullptr, 512,
      A, A + 524288, nullptr, 512, 256, 1, 262144);
  // attention -> pool (U1)
  attn_kernel<<<dim3(512, 8), 256, 0, stream>>>(A, bq2, bv2, kf, Mb, vf, U1);
  // g2 (g1 folded) = silu(U1@Wg + bg2): N=1024 s2 -> LL0,LL1
  gemm_p<1, 0><<<dim3(16, 8, 2), 256, 0, stream>>>(
      ap(U1, 512), ap(U1, 512), Wg, nullptr, nullptr, 1024,
      A, nullptr, nullptr, 1024, 256, 0, 524288);
  sumk<2, 1><<<512, 256, 0, stream>>>(A, 524288, bg2, 1023, XC);
  // g3 = XC@gp_w2: K=1024 s4 -> L0-L3 (ln consumes)
  gemm_p<1, 0><<<dim3(8, 8, 4), 256, 0, stream>>>(
      ap(XC, 1024), ap(XC, 1024), gp_w2, nullptr, nullptr, 512,
      A, nullptr, nullptr, 512, 256, 0, 262144);
  // ln(sum4 + gp_b2) -> LNOUT
  ln_kernel<<<512, 256, 0, stream>>>(A, gp_b2, ln_g, ln_b, LNOUT);
  // r1 = silu(LNOUT@dn_w1 + dn_b1): N=1024 s2 -> LL0,LL1
  gemm_p<1, 0><<<dim3(16, 8, 2), 256, 0, stream>>>(
      ap(LNOUT, 512), ap(LNOUT, 512), dn_w1, nullptr, nullptr, 1024,
      A, nullptr, nullptr, 1024, 256, 0, 524288);
  sumk<2, 1><<<512, 256, 0, stream>>>(A, 524288, dn_b1, 1023, XC2);
  // r2 = silu(XC2@dn_w2 + dn_b2): K=1024 N=1024 s4 -> whole arena
  gemm_p<1, 0><<<dim3(16, 8, 4), 256, 0, stream>>>(
      ap(XC2, 1024), ap(XC2, 1024), dn_w2, nullptr, nullptr, 1024,
      A, nullptr, nullptr, 1024, 256, 0, 524288);
  sumk<4, 1><<<512, 256, 0, stream>>>(A, 524288, dn_b2, 1023, XC3);
  // out = XC3@dn_w3[:, :128]: s16 -> L
  gemm_p<1, 0><<<dim3(2, 8, 16), 256, 0, stream>>>(
      ap(XC3, 1024), ap(XC3, 1024), dn_w3, nullptr, nullptr, 256,
      A, nullptr, nullptr, 128, 64, 0, 65536);
  // tanh(sum16 + dn_b3) -> d_out (f32)
  reduce_tanh<<<64, 256, 0, stream>>>(A, 65536, 16, dn_b3, (float*)d_out);
}